// Round 8
// baseline (69.687 us; speedup 1.0000x reference)
//
#include <hip/hip_runtime.h>
#include <hip/hip_bf16.h>
#include <cstdint>

typedef unsigned short u16;
typedef __bf16 bf16x8 __attribute__((ext_vector_type(8)));
typedef u16 u16x8 __attribute__((ext_vector_type(8)));
typedef unsigned u32x4 __attribute__((ext_vector_type(4)));
typedef float f32x2 __attribute__((ext_vector_type(2)));
typedef float f32x4 __attribute__((ext_vector_type(4)));
typedef float f32x16 __attribute__((ext_vector_type(16)));

#define B_ 2
#define S_ 2048
#define H_ 16
#define HS_ 64
#define EMB_ 1024
#define QSCALE 0.022097086912079608f  /* 1/sqrt(2048) */
#define LOG2E  1.4426950408889634f    /* folded into Q so softmax uses exp2 */

static __device__ __forceinline__ u16 f2bf(float f) {
  unsigned int u = __float_as_uint(f);
  u += 0x7fffu + ((u >> 16) & 1u);   // RNE
  return (u16)(u >> 16);
}

// single-instruction 2^x
static __device__ __forceinline__ float ex2(float x) {
#if __has_builtin(__builtin_amdgcn_exp2f)
  return __builtin_amdgcn_exp2f(x);
#else
  float r; asm("v_exp_f32 %0, %1" : "=v"(r) : "v"(x)); return r;
#endif
}

// depth-4 tree sum of 16 floats
static __device__ __forceinline__ float tsum16(const f32x16& s) {
  float a0 = s[0] + s[1],  a1 = s[2] + s[3];
  float a2 = s[4] + s[5],  a3 = s[6] + s[7];
  float a4 = s[8] + s[9],  a5 = s[10] + s[11];
  float a6 = s[12] + s[13], a7 = s[14] + s[15];
  a0 += a1; a2 += a3; a4 += a5; a6 += a7;
  a0 += a2; a4 += a6;
  return a0 + a4;
}

static __device__ __forceinline__ f32x4 mfma16(u16x8 a, u16x8 b, f32x4 c) {
  return __builtin_amdgcn_mfma_f32_16x16x32_bf16(
      __builtin_bit_cast(bf16x8, a), __builtin_bit_cast(bf16x8, b), c, 0, 0, 0);
}
static __device__ __forceinline__ f32x16 mfma32(u16x8 a, u16x8 b, f32x16 c) {
  return __builtin_amdgcn_mfma_f32_32x32x16_bf16(
      __builtin_bit_cast(bf16x8, a), __builtin_bit_cast(bf16x8, b), c, 0, 0, 0);
}

// XOR-swizzled address into a tile with 128B row stride (LDS bank-conflict fix).
static __device__ __forceinline__ char* swzb(void* base, int row, int colbyte) {
  return (char*)base + ((row * 128 + colbyte) ^ ((row & 7) << 4));
}
static __device__ __forceinline__ u16x8* swzp(void* base, int row, int colbyte) {
  return (u16x8*)swzb(base, row, colbyte);
}

// cvt_pk two f32 pairs to packed bf16 words, then permlane32_swap (T12).
static __device__ __forceinline__ void pk_swap(float a0, float a1, float b0, float b1,
                                               unsigned& x, unsigned& y) {
  unsigned A, Bv;
  asm("v_cvt_pk_bf16_f32 %0, %1, %2" : "=v"(A) : "v"(a0), "v"(a1));
  asm("v_cvt_pk_bf16_f32 %0, %1, %2" : "=v"(Bv) : "v"(b0), "v"(b1));
  asm("v_permlane32_swap_b32 %0, %1" : "+v"(A), "+v"(Bv));
  x = A; y = Bv;
}

static __device__ __forceinline__ void pack2(const f32x16& s0, u16x8& pf0, u16x8& pf1) {
  unsigned w0, w1, w2, w3;
  pk_swap(s0[0], s0[1], s0[4], s0[5], w0, w2);
  pk_swap(s0[2], s0[3], s0[6], s0[7], w1, w3);
  pf0 = __builtin_bit_cast(u16x8, (u32x4){w0, w1, w2, w3});
  pk_swap(s0[8], s0[9], s0[12], s0[13], w0, w2);
  pk_swap(s0[10], s0[11], s0[14], s0[15], w1, w3);
  pf1 = __builtin_bit_cast(u16x8, (u32x4){w0, w1, w2, w3});
}
static __device__ __forceinline__ void pack4(const f32x16& s0, const f32x16& s1,
                                             u16x8& pf0, u16x8& pf1, u16x8& pf2, u16x8& pf3) {
  pack2(s0, pf0, pf1);
  pack2(s1, pf2, pf3);
}

// ---------------- K0: Wo[k][n] fp32 -> Wot[n][k] bf16 ----------------
__global__ __launch_bounds__(256) void k_transpose_wo(const float* __restrict__ Wo,
                                                      u16* __restrict__ Wot) {
  __shared__ __align__(16) u16 T[64][72];
  const int kb = blockIdx.y * 64, nb = blockIdx.x * 64;
  const int r = threadIdx.x >> 2;
  const int c0 = (threadIdx.x & 3) << 4;
  const float* src = Wo + (size_t)(kb + r) * EMB_ + nb + c0;
#pragma unroll
  for (int i = 0; i < 16; i += 4) {
    float4 f = *(const float4*)(src + i);
    T[c0 + i + 0][r] = f2bf(f.x);
    T[c0 + i + 1][r] = f2bf(f.y);
    T[c0 + i + 2][r] = f2bf(f.z);
    T[c0 + i + 3][r] = f2bf(f.w);
  }
  __syncthreads();
  u16* dst = Wot + (size_t)(nb + r) * EMB_ + kb + c0;
  *(u16x8*)(dst)     = *(const u16x8*)&T[r][c0];
  *(u16x8*)(dst + 8) = *(const u16x8*)&T[r][c0 + 8];
}

// ---------------- K1: projections -> FRAGMENT-MAJOR layouts (tn = blockIdx.z) ----
// Qf: [bh][t:64][slice:4][lane:64][8]   = Q[t*32+(l&31)][slice*16+(l>>5)*8+j] * QSCALE*LOG2E
// Kf: [bh][tau:64][slice:4][lane:64][8] = K[tau*32+(l&31)][slice*16+(l>>5)*8+j]
// Vf: [bh][j:32][eta:2][kap:4][lane:64][8] = Vt[eta*32+(l&31)][j*64+kap*16+(l>>5)*8+jj]
__global__ __launch_bounds__(256) void k_proj(
    const float* __restrict__ xq, const float* __restrict__ xk, const float* __restrict__ xv,
    const float* __restrict__ Wq, const float* __restrict__ Wk, const float* __restrict__ Wv,
    u16* __restrict__ Qf, u16* __restrict__ Kf, u16* __restrict__ Vf) {
  __shared__ __align__(16) u16 Xb[64][64];
  __shared__ __align__(16) u16 Wb[64][64];   // Wb[e][d] = W[d][e]
  __shared__ __align__(16) u16 Tt[64][64];
  const int sb = blockIdx.x;   // s-block 0..31
  const int bh = blockIdx.y;   // 0..31
  const int tn = blockIdx.z;   // 0=Q, 1=K, 2=V
  const int b = bh >> 4, h = bh & 15;
  const int t = threadIdx.x;
  const int r = t >> 2, c0 = (t & 3) << 4;
  const int lane = t & 63, wv = t >> 6;
  const int lq = lane & 15, lg = lane >> 4;
  const int l31 = lane & 31, hi = lane >> 5;
  const float* xs = (tn == 0) ? xq : (tn == 1) ? xk : xv;
  const float* wsp3 = (tn == 0) ? Wq : (tn == 1) ? Wk : Wv;

  const float* src = xs + ((size_t)(b * S_ + sb * 64 + r)) * HS_ + c0;
#pragma unroll
  for (int i = 0; i < 16; i += 8) {
    float4 fa = *(const float4*)(src + i);
    float4 fb = *(const float4*)(src + i + 4);
    u16x8 v = {f2bf(fa.x), f2bf(fa.y), f2bf(fa.z), f2bf(fa.w),
               f2bf(fb.x), f2bf(fb.y), f2bf(fb.z), f2bf(fb.w)};
    *swzp(Xb, r, (c0 + i) * 2) = v;
  }
  const float* wsp = wsp3 + ((size_t)(h * HS_ + r)) * HS_ + c0;
#pragma unroll
  for (int i = 0; i < 16; i += 4) {
    float4 f = *(const float4*)(wsp + i);
    *(u16*)swzb(Wb, c0 + i + 0, r * 2) = f2bf(f.x);
    *(u16*)swzb(Wb, c0 + i + 1, r * 2) = f2bf(f.y);
    *(u16*)swzb(Wb, c0 + i + 2, r * 2) = f2bf(f.z);
    *(u16*)swzb(Wb, c0 + i + 3, r * 2) = f2bf(f.w);
  }
  __syncthreads();
  if (tn < 2) {
    u16x8 a0 = *swzp(Xb, wv * 16 + lq, lg * 16);
    u16x8 a1 = *swzp(Xb, wv * 16 + lq, 64 + lg * 16);
    const float osc = (tn == 0) ? (QSCALE * LOG2E) : 1.0f;
#pragma unroll
    for (int et = 0; et < 4; ++et) {
      u16x8 b0 = *swzp(Wb, et * 16 + lq, lg * 16);
      u16x8 b1 = *swzp(Wb, et * 16 + lq, 64 + lg * 16);
      f32x4 acc = {0.f, 0.f, 0.f, 0.f};
      acc = mfma16(a0, b0, acc);
      acc = mfma16(a1, b1, acc);
#pragma unroll
      for (int rr = 0; rr < 4; ++rr)
        *(u16*)swzb(Tt, wv * 16 + lg * 4 + rr, (et * 16 + lq) * 2) = f2bf(acc[rr] * osc);
    }
  } else {
    u16x8 xb0 = *swzp(Xb, wv * 16 + lq, lg * 16);
    u16x8 xb1 = *swzp(Xb, wv * 16 + lq, 64 + lg * 16);
#pragma unroll
    for (int et = 0; et < 4; ++et) {
      u16x8 a0 = *swzp(Wb, et * 16 + lq, lg * 16);
      u16x8 a1 = *swzp(Wb, et * 16 + lq, 64 + lg * 16);
      f32x4 acc = {0.f, 0.f, 0.f, 0.f};
      acc = mfma16(a0, xb0, acc);
      acc = mfma16(a1, xb1, acc);
#pragma unroll
      for (int rr = 0; rr < 4; ++rr)
        *(u16*)swzb(Tt, et * 16 + lg * 4 + rr, (wv * 16 + lq) * 2) = f2bf(acc[rr]);
    }
  }
  __syncthreads();
  if (tn < 2) {
    u16* dst = (tn == 0) ? Qf : Kf;
#pragma unroll
    for (int tl = 0; tl < 2; ++tl) {
      u16x8 v = *swzp(Tt, tl * 32 + l31, wv * 32 + hi * 16);
      size_t off = (((size_t)(bh * 64 + sb * 2 + tl)) * 4 + wv) * 512 + lane * 8;
      *(u16x8*)(dst + off) = v;
    }
  } else {
#pragma unroll
    for (int eta = 0; eta < 2; ++eta) {
      u16x8 v = *swzp(Tt, eta * 32 + l31, wv * 32 + hi * 16);
      size_t off = ((((size_t)(bh * 32 + sb)) * 2 + eta) * 4 + wv) * 512 + lane * 8;
      *(u16x8*)(Vf + off) = v;
    }
  }
}

// ---------------- K2: causal flash attention, 64 q-rows per wave ----------------
// q-group g = q-tiles {2g, 2g+1} (identical kv range n = g+1) -> each K/V tile read
// once serves 64 q rows (L2 traffic halved). Block = 4 waves, kv split in quarters
// (diag always in wave3's quarter, peeled). Phases g=p then g=31-p -> uniform blocks.
// No-max exp2 softmax (C init -16); partials pure sums; 4-way merge via LDS.
__global__ __launch_bounds__(256, 2) void k_attn(
    const u16* __restrict__ Qf, const u16* __restrict__ Kf, const u16* __restrict__ Vf,
    u16* __restrict__ Co) {
  __shared__ float Xch[3][64][66];               // waves 1-3 partials (f32x2-strided)
  __shared__ __align__(16) u16 OswE[32][64];     // epilogue transpose (even tile)
  __shared__ __align__(16) u16 OswO[32][64];     // epilogue transpose (odd tile)
  const int bid = blockIdx.x;
  const int xcd = bid & 7, idx = bid >> 3;       // idx 0..63; 4 bh per XCD (L2 locality)
  const int bh = (xcd << 2) | (idx & 3);
  const int p = idx >> 2;                        // 0..15
  const int b = bh >> 4, h = bh & 15;
  const int w = threadIdx.x >> 6;                // wave 0..3
  const int l = threadIdx.x & 63;
  const int lq = l & 31, hi = l >> 5;
  const float NEG = -3.0e38f;

  const u16* Kbase = Kf + ((size_t)(bh * 64) * 4) * 512 + l * 8;
  const u16* Vbase = Vf + ((size_t)(bh * 32) * 8) * 512 + l * 8;

#pragma unroll 1
  for (int ph = 0; ph < 2; ++ph) {
    const int g = ph ? (31 - p) : p;
    const int n = g + 1;                         // kv 64-tiles needed (same for both tiles)
    const int js = (w * n) >> 2;
    const int je = ((w + 1) * n) >> 2;           // wave3: je == n
    const int jhot = (w == 3) ? (n - 1) : je;    // diag peeled to wave3

    const u16* Qe = Qf + (((size_t)(bh * 64 + 2 * g)) * 4) * 512 + l * 8;
    u16x8 qfe[4], qfo[4];
#pragma unroll
    for (int ss = 0; ss < 4; ++ss) {
      qfe[ss] = *(const u16x8*)(Qe + ss * 512);
      qfo[ss] = *(const u16x8*)(Qe + (4 + ss) * 512);
    }

    f32x16 o0e, o1e, o0o, o1o;
#pragma unroll
    for (int r = 0; r < 16; ++r) { o0e[r] = 0.f; o1e[r] = 0.f; o0o[r] = 0.f; o1o[r] = 0.f; }
    float lle = 0.f, llo = 0.f;

    u16x8 kl[4], kh[4], vl[4], vh[4];
    if (js < je) {
      const u16* pk = Kbase + (size_t)js * 8 * 512;
      const u16* pv = Vbase + (size_t)js * 8 * 512;
#pragma unroll
      for (int ss = 0; ss < 4; ++ss) {
        kl[ss] = *(const u16x8*)(pk + ss * 512);
        kh[ss] = *(const u16x8*)(pk + (4 + ss) * 512);
        vl[ss] = *(const u16x8*)(pv + ss * 512);
        vh[ss] = *(const u16x8*)(pv + (4 + ss) * 512);
      }
    }

    for (int j = js; j < jhot; ++j) {
      const bool pre = (j + 1 < jhot) || (w == 3);   // next K/V will be consumed?
      u16x8 pf0, pf1, pf2, pf3;
      // ---- even q-tile (rows 64g .. 64g+31) ----
      {
        f32x16 s0, s1;
#pragma unroll
        for (int r = 0; r < 16; ++r) { s0[r] = -16.f; s1[r] = -16.f; }
        __builtin_amdgcn_s_setprio(1);
        s0 = mfma32(kl[0], qfe[0], s0);
        s0 = mfma32(kl[1], qfe[1], s0);
        s0 = mfma32(kl[2], qfe[2], s0);
        s0 = mfma32(kl[3], qfe[3], s0);
        s1 = mfma32(kh[0], qfe[0], s1);
        s1 = mfma32(kh[1], qfe[1], s1);
        s1 = mfma32(kh[2], qfe[2], s1);
        s1 = mfma32(kh[3], qfe[3], s1);
        __builtin_amdgcn_s_setprio(0);
#pragma unroll
        for (int r = 0; r < 16; ++r) s0[r] = ex2(s0[r]);
#pragma unroll
        for (int r = 0; r < 16; ++r) s1[r] = ex2(s1[r]);
        lle += tsum16(s0) + tsum16(s1);
        pack4(s0, s1, pf0, pf1, pf2, pf3);
        __builtin_amdgcn_s_setprio(1);
        o0e = mfma32(vl[0], pf0, o0e);
        o1e = mfma32(vh[0], pf0, o1e);
        o0e = mfma32(vl[1], pf1, o0e);
        o1e = mfma32(vh[1], pf1, o1e);
        o0e = mfma32(vl[2], pf2, o0e);
        o1e = mfma32(vh[2], pf2, o1e);
        o0e = mfma32(vl[3], pf3, o0e);
        o1e = mfma32(vh[3], pf3, o1e);
        __builtin_amdgcn_s_setprio(0);
      }
      // ---- odd q-tile (rows 64g+32 .. 64g+63) ----
      {
        f32x16 s0, s1;
#pragma unroll
        for (int r = 0; r < 16; ++r) { s0[r] = -16.f; s1[r] = -16.f; }
        __builtin_amdgcn_s_setprio(1);
        s0 = mfma32(kl[0], qfo[0], s0);
        s0 = mfma32(kl[1], qfo[1], s0);
        s0 = mfma32(kl[2], qfo[2], s0);
        s0 = mfma32(kl[3], qfo[3], s0);
        s1 = mfma32(kh[0], qfo[0], s1);
        s1 = mfma32(kh[1], qfo[1], s1);
        s1 = mfma32(kh[2], qfo[2], s1);
        s1 = mfma32(kh[3], qfo[3], s1);
        __builtin_amdgcn_s_setprio(0);
        if (pre) {  // K fully consumed for this j -> in-place prefetch
          const u16* pk = Kbase + (size_t)(j + 1) * 8 * 512;
#pragma unroll
          for (int ss = 0; ss < 4; ++ss) {
            kl[ss] = *(const u16x8*)(pk + ss * 512);
            kh[ss] = *(const u16x8*)(pk + (4 + ss) * 512);
          }
        }
#pragma unroll
        for (int r = 0; r < 16; ++r) s0[r] = ex2(s0[r]);
#pragma unroll
        for (int r = 0; r < 16; ++r) s1[r] = ex2(s1[r]);
        llo += tsum16(s0) + tsum16(s1);
        pack4(s0, s1, pf0, pf1, pf2, pf3);
        __builtin_amdgcn_s_setprio(1);
        o0o = mfma32(vl[0], pf0, o0o);
        o1o = mfma32(vh[0], pf0, o1o);
        o0o = mfma32(vl[1], pf1, o0o);
        o1o = mfma32(vh[1], pf1, o1o);
        o0o = mfma32(vl[2], pf2, o0o);
        o1o = mfma32(vh[2], pf2, o1o);
        o0o = mfma32(vl[3], pf3, o0o);
        o1o = mfma32(vh[3], pf3, o1o);
        __builtin_amdgcn_s_setprio(0);
        if (pre) {  // V fully consumed -> in-place prefetch
          const u16* pv = Vbase + (size_t)(j + 1) * 8 * 512;
#pragma unroll
          for (int ss = 0; ss < 4; ++ss) {
            vl[ss] = *(const u16x8*)(pv + ss * 512);
            vh[ss] = *(const u16x8*)(pv + (4 + ss) * 512);
          }
        }
      }
    }

    if (w == 3) {  // peeled diagonal tile j = n-1 (kl..vh hold it)
      u16x8 pf0, pf1, pf2, pf3;
      // even tile: kv high half fully masked -> s0 only, triangular mask
      {
        f32x16 s0;
#pragma unroll
        for (int r = 0; r < 16; ++r) s0[r] = -16.f;
        s0 = mfma32(kl[0], qfe[0], s0);
        s0 = mfma32(kl[1], qfe[1], s0);
        s0 = mfma32(kl[2], qfe[2], s0);
        s0 = mfma32(kl[3], qfe[3], s0);
#pragma unroll
        for (int r = 0; r < 16; ++r) {
          int crow = (r & 3) + 8 * (r >> 2) + 4 * hi;
          if (crow > lq) s0[r] = NEG;
        }
#pragma unroll
        for (int r = 0; r < 16; ++r) s0[r] = ex2(s0[r]);
        lle += tsum16(s0);
        pack2(s0, pf0, pf1);
        o0e = mfma32(vl[0], pf0, o0e);
        o1e = mfma32(vh[0], pf0, o1e);
        o0e = mfma32(vl[1], pf1, o0e);
        o1e = mfma32(vh[1], pf1, o1e);
      }
      // odd tile: kv low half full, high half triangular
      {
        f32x16 s0, s1;
#pragma unroll
        for (int r = 0; r < 16; ++r) { s0[r] = -16.f; s1[r] = -16.f; }
        s0 = mfma32(kl[0], qfo[0], s0);
        s0 = mfma32(kl[1], qfo[1], s0);
        s0 = mfma32(kl[2], qfo[2], s0);
        s0 = mfma32(kl[3], qfo[3], s0);
        s1 = mfma32(kh[0], qfo[0], s1);
        s1 = mfma32(kh[1], qfo[1], s1);
        s1 = mfma32(kh[2], qfo[2], s1);
        s1 = mfma32(kh[3], qfo[3], s1);
#pragma unroll
        for (int r = 0; r < 16; ++r) {
          int crow = (r & 3) + 8 * (r >> 2) + 4 * hi;
          if (crow > lq) s1[r] = NEG;
        }
#pragma unroll
        for (int r = 0; r < 16; ++r) s0[r] = ex2(s0[r]);
#pragma unroll
        for (int r = 0; r < 16; ++r) s1[r] = ex2(s1[r]);
        llo += tsum16(s0) + tsum16(s1);
        pack4(s0, s1, pf0, pf1, pf2, pf3);
        o0o = mfma32(vl[0], pf0, o0o);
        o1o = mfma32(vh[0], pf0, o1o);
        o0o = mfma32(vl[1], pf1, o0o);
        o1o = mfma32(vh[1], pf1, o1o);
        o0o = mfma32(vl[2], pf2, o0o);
        o1o = mfma32(vh[2], pf2, o1o);
        o0o = mfma32(vl[3], pf3, o0o);
        o1o = mfma32(vh[3], pf3, o1o);
      }
    }

    // ---- 4-way merge (pure sums) ----
    if (w) {
      f32x2* xr = (f32x2*)(&Xch[w - 1][l][0]);
#pragma unroll
      for (int i = 0; i < 8; ++i) {
        xr[i]      = (f32x2){o0e[2 * i], o0e[2 * i + 1]};
        xr[8 + i]  = (f32x2){o1e[2 * i], o1e[2 * i + 1]};
        xr[16 + i] = (f32x2){o0o[2 * i], o0o[2 * i + 1]};
        xr[24 + i] = (f32x2){o1o[2 * i], o1o[2 * i + 1]};
      }
      xr[32] = (f32x2){lle, llo};
    }
    __syncthreads();
    if (w == 0) {
#pragma unroll
      for (int wv = 0; wv < 3; ++wv) {
        const f32x2* xr = (const f32x2*)(&Xch[wv][l][0]);
#pragma unroll
        for (int i = 0; i < 8; ++i) {
          f32x2 a = xr[i], bq = xr[8 + i], c = xr[16 + i], d = xr[24 + i];
          o0e[2 * i] += a[0]; o0e[2 * i + 1] += a[1];
          o1e[2 * i] += bq[0]; o1e[2 * i + 1] += bq[1];
          o0o[2 * i] += c[0]; o0o[2 * i + 1] += c[1];
          o1o[2 * i] += d[0]; o1o[2 * i + 1] += d[1];
        }
        f32x2 e = xr[32];
        lle += e[0]; llo += e[1];
      }
      lle += __shfl_xor(lle, 32);
      llo += __shfl_xor(llo, 32);
      // epilogue even tile
      {
        float inv = 1.0f / lle;
#pragma unroll
        for (int r = 0; r < 16; ++r) {
          int drow = (r & 3) + 8 * (r >> 2) + 4 * hi;
          *(u16*)swzb(OswE, lq, drow * 2) = f2bf(o0e[r] * inv);
          *(u16*)swzb(OswE, lq, (32 + drow) * 2) = f2bf(o1e[r] * inv);
        }
        u16* dst = Co + ((size_t)(b * S_ + 64 * g + lq)) * EMB_ + h * HS_ + hi * 32;
#pragma unroll
        for (int k = 0; k < 4; ++k) {
          u16x8 vv = *swzp(OswE, lq, (hi * 32 + k * 8) * 2);
          *(u16x8*)(dst + k * 8) = vv;
        }
      }
      // epilogue odd tile
      {
        float inv = 1.0f / llo;
#pragma unroll
        for (int r = 0; r < 16; ++r) {
          int drow = (r & 3) + 8 * (r >> 2) + 4 * hi;
          *(u16*)swzb(OswO, lq, drow * 2) = f2bf(o0o[r] * inv);
          *(u16*)swzb(OswO, lq, (32 + drow) * 2) = f2bf(o1o[r] * inv);
        }
        u16* dst = Co + ((size_t)(b * S_ + 64 * g + 32 + lq)) * EMB_ + h * HS_ + hi * 32;
#pragma unroll
        for (int k = 0; k < 4; ++k) {
          u16x8 vv = *swzp(OswO, lq, (hi * 32 + k * 8) * 2);
          *(u16x8*)(dst + k * 8) = vv;
        }
      }
    }
    __syncthreads();   // protect Xch/Osw before next phase
  }
}

// ---------------- K3: out = concat @ Wo + bo (fp32 out), 64x128 tiles ----------------
__global__ __launch_bounds__(256) void k_outproj(
    const u16* __restrict__ Cc, const u16* __restrict__ Wot,
    const float* __restrict__ bo, float* __restrict__ out) {
  __shared__ __align__(16) u16 As[64][64];
  __shared__ __align__(16) u16 Bs[128][64];
  const int bid = blockIdx.x;
  const int xcd = bid & 7, sl = bid >> 3;
  const int mb = (xcd << 3) | (sl >> 3);
  const int nb = sl & 7;
  const int t = threadIdx.x;
  const int lane = t & 63, wv = t >> 6;
  const int lq = lane & 15, lg = lane >> 4;
  const int wr = wv >> 1, wc = wv & 1;
  const int srA = t >> 2, scA = (t & 3) << 4;
  const int srB = t >> 1, scB = (t & 1) << 5;
  f32x4 acc[2][4];
#pragma unroll
  for (int mi = 0; mi < 2; ++mi)
#pragma unroll
    for (int ni = 0; ni < 4; ++ni) { f32x4 z = {0.f, 0.f, 0.f, 0.f}; acc[mi][ni] = z; }
  const u16* abase = Cc + ((size_t)(mb * 64 + srA)) * EMB_ + scA;
  const u16* bbase = Wot + ((size_t)(nb * 128 + srB)) * EMB_ + scB;
  u16x8 ar[2], br[4];
#pragma unroll
  for (int q = 0; q < 2; ++q) ar[q] = *(const u16x8*)(abase + q * 8);
#pragma unroll
  for (int q = 0; q < 4; ++q) br[q] = *(const u16x8*)(bbase + q * 8);
  for (int kt = 0; kt < 16; ++kt) {
    __syncthreads();
#pragma unroll
    for (int q = 0; q < 2; ++q) *swzp(As, srA, (scA + q * 8) * 2) = ar[q];
#pragma unroll
    for (int q = 0; q < 4; ++q) *swzp(Bs, srB, (scB + q * 8) * 2) = br[q];
    __syncthreads();
    if (kt < 15) {
#pragma unroll
      for (int q = 0; q < 2; ++q) ar[q] = *(const u16x8*)(abase + (kt + 1) * 64 + q * 8);
#pragma unroll
      for (int q = 0; q < 4; ++q) br[q] = *(const u16x8*)(bbase + (kt + 1) * 64 + q * 8);
    }
#pragma unroll
    for (int kf = 0; kf < 2; ++kf) {
      u16x8 af[2], bf[4];
#pragma unroll
      for (int mi = 0; mi < 2; ++mi)
        af[mi] = *swzp(As, wr * 32 + mi * 16 + lq, kf * 64 + lg * 16);
#pragma unroll
      for (int ni = 0; ni < 4; ++ni)
        bf[ni] = *swzp(Bs, wc * 64 + ni * 16 + lq, kf * 64 + lg * 16);
#pragma unroll
      for (int mi = 0; mi < 2; ++mi)
#pragma unroll
        for (int ni = 0; ni < 4; ++ni)
          acc[mi][ni] = mfma16(af[mi], bf[ni], acc[mi][ni]);
    }
  }
#pragma unroll
  for (int mi = 0; mi < 2; ++mi) {
#pragma unroll
    for (int ni = 0; ni < 4; ++ni) {
      int col = nb * 128 + wc * 64 + ni * 16 + lq;
      float bv = bo[col];
#pragma unroll
      for (int rr = 0; rr < 4; ++rr) {
        int row = mb * 64 + wr * 32 + mi * 16 + lg * 4 + rr;
        out[(size_t)row * EMB_ + col] = acc[mi][ni][rr] + bv;
      }
    }
  }
}

extern "C" void kernel_launch(void* const* d_in, const int* in_sizes, int n_in,
                              void* d_out, int out_size, void* d_ws, size_t ws_size,
                              hipStream_t stream) {
  const float* xk = (const float*)d_in[0];
  const float* xv = (const float*)d_in[1];
  const float* xq = (const float*)d_in[2];
  const float* Wk = (const float*)d_in[3];
  const float* Wv = (const float*)d_in[4];
  const float* Wq = (const float*)d_in[5];
  const float* Wo = (const float*)d_in[6];
  const float* bo = (const float*)d_in[7];
  float* out = (float*)d_out;
  char* ws = (char*)d_ws;
  const size_t MB8 = (size_t)8 * 1024 * 1024;
  u16* Qfw = (u16*)(ws);             // fragment-major Q (pre-scaled, exp2 domain)
  u16* Kfw = (u16*)(ws + MB8);       // fragment-major K
  u16* Vfw = (u16*)(ws + 2 * MB8);   // fragment-major V^T
  u16* Cw  = (u16*)(ws + 3 * MB8);   // concat [2][2048][1024]
  u16* Wot = (u16*)(ws + 4 * MB8);   // [1024][1024]

  k_transpose_wo<<<dim3(16, 16), 256, 0, stream>>>(Wo, Wot);
  k_proj<<<dim3(32, 32, 3), 256, 0, stream>>>(xq, xk, xv, Wq, Wk, Wv, Qfw, Kfw, Vfw);
  k_attn<<<512, 256, 0, stream>>>(Qfw, Kfw, Vfw, Cw);
  k_outproj<<<512, 256, 0, stream>>>(Cw, Wot, bo, out);
}

// Round 9
// 66.062 us; speedup vs baseline: 1.0549x; 1.0549x over previous
//
#include <hip/hip_runtime.h>
#include <hip/hip_bf16.h>
#include <cstdint>

typedef unsigned short u16;
typedef __bf16 bf16x8 __attribute__((ext_vector_type(8)));
typedef u16 u16x8 __attribute__((ext_vector_type(8)));
typedef unsigned u32x4 __attribute__((ext_vector_type(4)));
typedef float f32x2 __attribute__((ext_vector_type(2)));
typedef float f32x4 __attribute__((ext_vector_type(4)));
typedef float f32x16 __attribute__((ext_vector_type(16)));

#define B_ 2
#define S_ 2048
#define H_ 16
#define HS_ 64
#define EMB_ 1024
#define QSCALE 0.022097086912079608f  /* 1/sqrt(2048) */
#define LOG2E  1.4426950408889634f    /* folded into Q so softmax uses exp2 */

static __device__ __forceinline__ u16 f2bf(float f) {
  unsigned int u = __float_as_uint(f);
  u += 0x7fffu + ((u >> 16) & 1u);   // RNE
  return (u16)(u >> 16);
}

// single-instruction 2^x
static __device__ __forceinline__ float ex2(float x) {
#if __has_builtin(__builtin_amdgcn_exp2f)
  return __builtin_amdgcn_exp2f(x);
#else
  float r; asm("v_exp_f32 %0, %1" : "=v"(r) : "v"(x)); return r;
#endif
}

// depth-4 tree sum of 16 floats
static __device__ __forceinline__ float tsum16(const f32x16& s) {
  float a0 = s[0] + s[1],  a1 = s[2] + s[3];
  float a2 = s[4] + s[5],  a3 = s[6] + s[7];
  float a4 = s[8] + s[9],  a5 = s[10] + s[11];
  float a6 = s[12] + s[13], a7 = s[14] + s[15];
  a0 += a1; a2 += a3; a4 += a5; a6 += a7;
  a0 += a2; a4 += a6;
  return a0 + a4;
}

static __device__ __forceinline__ f32x4 mfma16(u16x8 a, u16x8 b, f32x4 c) {
  return __builtin_amdgcn_mfma_f32_16x16x32_bf16(
      __builtin_bit_cast(bf16x8, a), __builtin_bit_cast(bf16x8, b), c, 0, 0, 0);
}
static __device__ __forceinline__ f32x16 mfma32(u16x8 a, u16x8 b, f32x16 c) {
  return __builtin_amdgcn_mfma_f32_32x32x16_bf16(
      __builtin_bit_cast(bf16x8, a), __builtin_bit_cast(bf16x8, b), c, 0, 0, 0);
}

// XOR-swizzled address into a tile with 128B row stride (LDS bank-conflict fix).
static __device__ __forceinline__ char* swzb(void* base, int row, int colbyte) {
  return (char*)base + ((row * 128 + colbyte) ^ ((row & 7) << 4));
}
static __device__ __forceinline__ u16x8* swzp(void* base, int row, int colbyte) {
  return (u16x8*)swzb(base, row, colbyte);
}

// cvt_pk two f32 pairs to packed bf16 words, then permlane32_swap (T12).
static __device__ __forceinline__ void pk_swap(float a0, float a1, float b0, float b1,
                                               unsigned& x, unsigned& y) {
  unsigned A, Bv;
  asm("v_cvt_pk_bf16_f32 %0, %1, %2" : "=v"(A) : "v"(a0), "v"(a1));
  asm("v_cvt_pk_bf16_f32 %0, %1, %2" : "=v"(Bv) : "v"(b0), "v"(b1));
  asm("v_permlane32_swap_b32 %0, %1" : "+v"(A), "+v"(Bv));
  x = A; y = Bv;
}

// P (16 f32 = one 32-kv half-tile for one q-tile) -> two PV B-fragments
static __device__ __forceinline__ void pack2(const f32x16& s0, u16x8& pf0, u16x8& pf1) {
  unsigned w0, w1, w2, w3;
  pk_swap(s0[0], s0[1], s0[4], s0[5], w0, w2);
  pk_swap(s0[2], s0[3], s0[6], s0[7], w1, w3);
  pf0 = __builtin_bit_cast(u16x8, (u32x4){w0, w1, w2, w3});
  pk_swap(s0[8], s0[9], s0[12], s0[13], w0, w2);
  pk_swap(s0[10], s0[11], s0[14], s0[15], w1, w3);
  pf1 = __builtin_bit_cast(u16x8, (u32x4){w0, w1, w2, w3});
}

// ---------------- K0: Wo[k][n] fp32 -> Wot[n][k] bf16 ----------------
__global__ __launch_bounds__(256) void k_transpose_wo(const float* __restrict__ Wo,
                                                      u16* __restrict__ Wot) {
  __shared__ __align__(16) u16 T[64][72];
  const int kb = blockIdx.y * 64, nb = blockIdx.x * 64;
  const int r = threadIdx.x >> 2;
  const int c0 = (threadIdx.x & 3) << 4;
  const float* src = Wo + (size_t)(kb + r) * EMB_ + nb + c0;
#pragma unroll
  for (int i = 0; i < 16; i += 4) {
    float4 f = *(const float4*)(src + i);
    T[c0 + i + 0][r] = f2bf(f.x);
    T[c0 + i + 1][r] = f2bf(f.y);
    T[c0 + i + 2][r] = f2bf(f.z);
    T[c0 + i + 3][r] = f2bf(f.w);
  }
  __syncthreads();
  u16* dst = Wot + (size_t)(nb + r) * EMB_ + kb + c0;
  *(u16x8*)(dst)     = *(const u16x8*)&T[r][c0];
  *(u16x8*)(dst + 8) = *(const u16x8*)&T[r][c0 + 8];
}

// ---------------- K1: projections -> FRAGMENT-MAJOR layouts (tn = blockIdx.z) ----
// Qf: [bh][t:64][slice:4][lane:64][8]   = Q[t*32+(l&31)][slice*16+(l>>5)*8+j] * QSCALE*LOG2E
// Kf: [bh][tau:64][slice:4][lane:64][8] = K[tau*32+(l&31)][slice*16+(l>>5)*8+j]
// Vf: [bh][j:32][eta:2][kap:4][lane:64][8] = Vt[eta*32+(l&31)][j*64+kap*16+(l>>5)*8+jj]
__global__ __launch_bounds__(256) void k_proj(
    const float* __restrict__ xq, const float* __restrict__ xk, const float* __restrict__ xv,
    const float* __restrict__ Wq, const float* __restrict__ Wk, const float* __restrict__ Wv,
    u16* __restrict__ Qf, u16* __restrict__ Kf, u16* __restrict__ Vf) {
  __shared__ __align__(16) u16 Xb[64][64];
  __shared__ __align__(16) u16 Wb[64][64];   // Wb[e][d] = W[d][e]
  __shared__ __align__(16) u16 Tt[64][64];
  const int sb = blockIdx.x;   // s-block 0..31
  const int bh = blockIdx.y;   // 0..31
  const int tn = blockIdx.z;   // 0=Q, 1=K, 2=V
  const int b = bh >> 4, h = bh & 15;
  const int t = threadIdx.x;
  const int r = t >> 2, c0 = (t & 3) << 4;
  const int lane = t & 63, wv = t >> 6;
  const int lq = lane & 15, lg = lane >> 4;
  const int l31 = lane & 31, hi = lane >> 5;
  const float* xs = (tn == 0) ? xq : (tn == 1) ? xk : xv;
  const float* wsp3 = (tn == 0) ? Wq : (tn == 1) ? Wk : Wv;

  const float* src = xs + ((size_t)(b * S_ + sb * 64 + r)) * HS_ + c0;
#pragma unroll
  for (int i = 0; i < 16; i += 8) {
    float4 fa = *(const float4*)(src + i);
    float4 fb = *(const float4*)(src + i + 4);
    u16x8 v = {f2bf(fa.x), f2bf(fa.y), f2bf(fa.z), f2bf(fa.w),
               f2bf(fb.x), f2bf(fb.y), f2bf(fb.z), f2bf(fb.w)};
    *swzp(Xb, r, (c0 + i) * 2) = v;
  }
  const float* wsp = wsp3 + ((size_t)(h * HS_ + r)) * HS_ + c0;
#pragma unroll
  for (int i = 0; i < 16; i += 4) {
    float4 f = *(const float4*)(wsp + i);
    *(u16*)swzb(Wb, c0 + i + 0, r * 2) = f2bf(f.x);
    *(u16*)swzb(Wb, c0 + i + 1, r * 2) = f2bf(f.y);
    *(u16*)swzb(Wb, c0 + i + 2, r * 2) = f2bf(f.z);
    *(u16*)swzb(Wb, c0 + i + 3, r * 2) = f2bf(f.w);
  }
  __syncthreads();
  if (tn < 2) {
    u16x8 a0 = *swzp(Xb, wv * 16 + lq, lg * 16);
    u16x8 a1 = *swzp(Xb, wv * 16 + lq, 64 + lg * 16);
    const float osc = (tn == 0) ? (QSCALE * LOG2E) : 1.0f;
#pragma unroll
    for (int et = 0; et < 4; ++et) {
      u16x8 b0 = *swzp(Wb, et * 16 + lq, lg * 16);
      u16x8 b1 = *swzp(Wb, et * 16 + lq, 64 + lg * 16);
      f32x4 acc = {0.f, 0.f, 0.f, 0.f};
      acc = mfma16(a0, b0, acc);
      acc = mfma16(a1, b1, acc);
#pragma unroll
      for (int rr = 0; rr < 4; ++rr)
        *(u16*)swzb(Tt, wv * 16 + lg * 4 + rr, (et * 16 + lq) * 2) = f2bf(acc[rr] * osc);
    }
  } else {
    u16x8 xb0 = *swzp(Xb, wv * 16 + lq, lg * 16);
    u16x8 xb1 = *swzp(Xb, wv * 16 + lq, 64 + lg * 16);
#pragma unroll
    for (int et = 0; et < 4; ++et) {
      u16x8 a0 = *swzp(Wb, et * 16 + lq, lg * 16);
      u16x8 a1 = *swzp(Wb, et * 16 + lq, 64 + lg * 16);
      f32x4 acc = {0.f, 0.f, 0.f, 0.f};
      acc = mfma16(a0, xb0, acc);
      acc = mfma16(a1, xb1, acc);
#pragma unroll
      for (int rr = 0; rr < 4; ++rr)
        *(u16*)swzb(Tt, et * 16 + lg * 4 + rr, (wv * 16 + lq) * 2) = f2bf(acc[rr]);
    }
  }
  __syncthreads();
  if (tn < 2) {
    u16* dst = (tn == 0) ? Qf : Kf;
#pragma unroll
    for (int tl = 0; tl < 2; ++tl) {
      u16x8 v = *swzp(Tt, tl * 32 + l31, wv * 32 + hi * 16);
      size_t off = (((size_t)(bh * 64 + sb * 2 + tl)) * 4 + wv) * 512 + lane * 8;
      *(u16x8*)(dst + off) = v;
    }
  } else {
#pragma unroll
    for (int eta = 0; eta < 2; ++eta) {
      u16x8 v = *swzp(Tt, eta * 32 + l31, wv * 32 + hi * 16);
      size_t off = ((((size_t)(bh * 32 + sb)) * 2 + eta) * 4 + wv) * 512 + lane * 8;
      *(u16x8*)(Vf + off) = v;
    }
  }
}

// ---------------- K2: causal flash attention, 64 q-rows/wave, 32-kv steps ----------
// Reuse: each 32-kv K/V fragment read serves BOTH q-tiles {2g, 2g+1} (L2 traffic
// halved vs 32-row waves). Register-lean: one K buf (16), one V buf (16), one score
// buf (16) live at a time; even/odd q-tiles processed sequentially per step.
// Block = 4 waves = kv quarters; phases g=p, 31-p (uniform); diag peeled (d0/d1).
__global__ __launch_bounds__(256, 2) void k_attn(
    const u16* __restrict__ Qf, const u16* __restrict__ Kf, const u16* __restrict__ Vf,
    u16* __restrict__ Co) {
  __shared__ float Xch[3][64][66];               // waves 1-3 partials
  __shared__ __align__(16) u16 OswE[32][64];
  __shared__ __align__(16) u16 OswO[32][64];
  const int bid = blockIdx.x;
  const int xcd = bid & 7, idx = bid >> 3;
  const int bh = (xcd << 2) | (idx & 3);
  const int p = idx >> 2;                        // 0..15
  const int b = bh >> 4, h = bh & 15;
  const int w = threadIdx.x >> 6;                // wave 0..3
  const int l = threadIdx.x & 63;
  const int lq = l & 31, hi = l >> 5;
  const float NEG = -3.0e38f;

  const u16* Kbase = Kf + ((size_t)(bh * 64) * 4) * 512 + l * 8;   // per 32-kv tau
  const u16* Vbase = Vf + ((size_t)(bh * 32) * 8) * 512 + l * 8;   // per 64-kv j

#pragma unroll 1
  for (int ph = 0; ph < 2; ++ph) {
    const int g = ph ? (31 - p) : p;
    const int n = g + 1;                         // 64-kv tiles needed
    const int js = (w * n) >> 2;
    const int je = ((w + 1) * n) >> 2;
    const bool dw = (w == 3);                    // diag owner
    const int t32s = 2 * js;
    const int t32e = dw ? 2 * (n - 1) : 2 * je;  // 32-kv loop end (diag excluded)
    const int tlim = dw ? t32e + 1 : t32e;       // prefetch validity bound

    const u16* Qe = Qf + (((size_t)(bh * 64 + 2 * g)) * 4) * 512 + l * 8;
    u16x8 qfe[4], qfo[4];
#pragma unroll
    for (int ss = 0; ss < 4; ++ss) {
      qfe[ss] = *(const u16x8*)(Qe + ss * 512);
      qfo[ss] = *(const u16x8*)(Qe + (4 + ss) * 512);
    }

    f32x16 o0e, o1e, o0o, o1o;
#pragma unroll
    for (int r = 0; r < 16; ++r) { o0e[r] = 0.f; o1e[r] = 0.f; o0o[r] = 0.f; o1o[r] = 0.f; }
    float lle = 0.f, llo = 0.f;

    u16x8 kf4[4], vf4[4];
    const bool havework = dw || (js < je);
    if (havework) {  // prologue: first 32-kv step's K and V
      const u16* pk = Kbase + ((size_t)t32s * 4) * 512;
      size_t vb = ((size_t)(t32s >> 1) * 8 + (size_t)(t32s & 1) * 2);
#pragma unroll
      for (int ss = 0; ss < 4; ++ss) kf4[ss] = *(const u16x8*)(pk + ss * 512);
      vf4[0] = *(const u16x8*)(Vbase + (vb + 0) * 512);
      vf4[1] = *(const u16x8*)(Vbase + (vb + 1) * 512);
      vf4[2] = *(const u16x8*)(Vbase + (vb + 4) * 512);
      vf4[3] = *(const u16x8*)(Vbase + (vb + 5) * 512);
    }

    for (int t32 = t32s; t32 < t32e; ++t32) {
      const bool pre = (t32 + 1 < tlim);
      u16x8 pfA, pfB;
      f32x16 s;
      // ---- even q-tile ----
#pragma unroll
      for (int r = 0; r < 16; ++r) s[r] = -16.f;
      __builtin_amdgcn_s_setprio(1);
      s = mfma32(kf4[0], qfe[0], s);
      s = mfma32(kf4[1], qfe[1], s);
      s = mfma32(kf4[2], qfe[2], s);
      s = mfma32(kf4[3], qfe[3], s);
      __builtin_amdgcn_s_setprio(0);
#pragma unroll
      for (int r = 0; r < 16; ++r) s[r] = ex2(s[r]);
      lle += tsum16(s);
      pack2(s, pfA, pfB);
      __builtin_amdgcn_s_setprio(1);
      o0e = mfma32(vf4[0], pfA, o0e);
      o0e = mfma32(vf4[1], pfB, o0e);
      o1e = mfma32(vf4[2], pfA, o1e);
      o1e = mfma32(vf4[3], pfB, o1e);
      __builtin_amdgcn_s_setprio(0);
      // ---- odd q-tile (K dies after these issue) ----
#pragma unroll
      for (int r = 0; r < 16; ++r) s[r] = -16.f;
      __builtin_amdgcn_s_setprio(1);
      s = mfma32(kf4[0], qfo[0], s);
      s = mfma32(kf4[1], qfo[1], s);
      s = mfma32(kf4[2], qfo[2], s);
      s = mfma32(kf4[3], qfo[3], s);
      __builtin_amdgcn_s_setprio(0);
      if (pre) {  // in-place K prefetch
        const u16* pk = Kbase + ((size_t)(t32 + 1) * 4) * 512;
#pragma unroll
        for (int ss = 0; ss < 4; ++ss) kf4[ss] = *(const u16x8*)(pk + ss * 512);
      }
#pragma unroll
      for (int r = 0; r < 16; ++r) s[r] = ex2(s[r]);
      llo += tsum16(s);
      pack2(s, pfA, pfB);
      __builtin_amdgcn_s_setprio(1);
      o0o = mfma32(vf4[0], pfA, o0o);
      o0o = mfma32(vf4[1], pfB, o0o);
      o1o = mfma32(vf4[2], pfA, o1o);
      o1o = mfma32(vf4[3], pfB, o1o);
      __builtin_amdgcn_s_setprio(0);
      if (pre) {  // in-place V prefetch
        size_t vb = ((size_t)((t32 + 1) >> 1) * 8 + (size_t)((t32 + 1) & 1) * 2);
        vf4[0] = *(const u16x8*)(Vbase + (vb + 0) * 512);
        vf4[1] = *(const u16x8*)(Vbase + (vb + 1) * 512);
        vf4[2] = *(const u16x8*)(Vbase + (vb + 4) * 512);
        vf4[3] = *(const u16x8*)(Vbase + (vb + 5) * 512);
      }
    }

    if (dw) {  // peeled diagonal 64-kv tile: d0 = low 32 kv, d1 = high 32 kv
      // load d1's K/V into a second small buffer NOW (hides under d0 compute)
      u16x8 kf2[4], vf2[4];
      {
        const int t1 = 2 * n - 1;
        const u16* pk = Kbase + ((size_t)t1 * 4) * 512;
        size_t vb = ((size_t)(t1 >> 1) * 8 + (size_t)(t1 & 1) * 2);
#pragma unroll
        for (int ss = 0; ss < 4; ++ss) kf2[ss] = *(const u16x8*)(pk + ss * 512);
        vf2[0] = *(const u16x8*)(Vbase + (vb + 0) * 512);
        vf2[1] = *(const u16x8*)(Vbase + (vb + 1) * 512);
        vf2[2] = *(const u16x8*)(Vbase + (vb + 4) * 512);
        vf2[3] = *(const u16x8*)(Vbase + (vb + 5) * 512);
      }
      u16x8 pfA, pfB;
      f32x16 s;
      // d0, even tile: triangular mask (crow > lq)
#pragma unroll
      for (int r = 0; r < 16; ++r) s[r] = -16.f;
      s = mfma32(kf4[0], qfe[0], s);
      s = mfma32(kf4[1], qfe[1], s);
      s = mfma32(kf4[2], qfe[2], s);
      s = mfma32(kf4[3], qfe[3], s);
#pragma unroll
      for (int r = 0; r < 16; ++r) {
        int crow = (r & 3) + 8 * (r >> 2) + 4 * hi;
        if (crow > lq) s[r] = NEG;
      }
#pragma unroll
      for (int r = 0; r < 16; ++r) s[r] = ex2(s[r]);
      lle += tsum16(s);
      pack2(s, pfA, pfB);
      o0e = mfma32(vf4[0], pfA, o0e);
      o0e = mfma32(vf4[1], pfB, o0e);
      o1e = mfma32(vf4[2], pfA, o1e);
      o1e = mfma32(vf4[3], pfB, o1e);
      // d0, odd tile: fully visible
#pragma unroll
      for (int r = 0; r < 16; ++r) s[r] = -16.f;
      s = mfma32(kf4[0], qfo[0], s);
      s = mfma32(kf4[1], qfo[1], s);
      s = mfma32(kf4[2], qfo[2], s);
      s = mfma32(kf4[3], qfo[3], s);
#pragma unroll
      for (int r = 0; r < 16; ++r) s[r] = ex2(s[r]);
      llo += tsum16(s);
      pack2(s, pfA, pfB);
      o0o = mfma32(vf4[0], pfA, o0o);
      o0o = mfma32(vf4[1], pfB, o0o);
      o1o = mfma32(vf4[2], pfA, o1o);
      o1o = mfma32(vf4[3], pfB, o1o);
      // d1, odd tile only: triangular mask (crow > lq); even tile fully masked
#pragma unroll
      for (int r = 0; r < 16; ++r) s[r] = -16.f;
      s = mfma32(kf2[0], qfo[0], s);
      s = mfma32(kf2[1], qfo[1], s);
      s = mfma32(kf2[2], qfo[2], s);
      s = mfma32(kf2[3], qfo[3], s);
#pragma unroll
      for (int r = 0; r < 16; ++r) {
        int crow = (r & 3) + 8 * (r >> 2) + 4 * hi;
        if (crow > lq) s[r] = NEG;
      }
#pragma unroll
      for (int r = 0; r < 16; ++r) s[r] = ex2(s[r]);
      llo += tsum16(s);
      pack2(s, pfA, pfB);
      o0o = mfma32(vf2[0], pfA, o0o);
      o0o = mfma32(vf2[1], pfB, o0o);
      o1o = mfma32(vf2[2], pfA, o1o);
      o1o = mfma32(vf2[3], pfB, o1o);
    }

    // ---- 4-way merge (pure sums) ----
    if (w) {
      f32x2* xr = (f32x2*)(&Xch[w - 1][l][0]);
#pragma unroll
      for (int i = 0; i < 8; ++i) {
        xr[i]      = (f32x2){o0e[2 * i], o0e[2 * i + 1]};
        xr[8 + i]  = (f32x2){o1e[2 * i], o1e[2 * i + 1]};
        xr[16 + i] = (f32x2){o0o[2 * i], o0o[2 * i + 1]};
        xr[24 + i] = (f32x2){o1o[2 * i], o1o[2 * i + 1]};
      }
      xr[32] = (f32x2){lle, llo};
    }
    __syncthreads();
    if (w == 0) {
#pragma unroll
      for (int wv = 0; wv < 3; ++wv) {
        const f32x2* xr = (const f32x2*)(&Xch[wv][l][0]);
#pragma unroll
        for (int i = 0; i < 8; ++i) {
          f32x2 a = xr[i], bq = xr[8 + i], c = xr[16 + i], d = xr[24 + i];
          o0e[2 * i] += a[0]; o0e[2 * i + 1] += a[1];
          o1e[2 * i] += bq[0]; o1e[2 * i + 1] += bq[1];
          o0o[2 * i] += c[0]; o0o[2 * i + 1] += c[1];
          o1o[2 * i] += d[0]; o1o[2 * i + 1] += d[1];
        }
        f32x2 e = xr[32];
        lle += e[0]; llo += e[1];
      }
      lle += __shfl_xor(lle, 32);
      llo += __shfl_xor(llo, 32);
      {
        float inv = 1.0f / lle;
#pragma unroll
        for (int r = 0; r < 16; ++r) {
          int drow = (r & 3) + 8 * (r >> 2) + 4 * hi;
          *(u16*)swzb(OswE, lq, drow * 2) = f2bf(o0e[r] * inv);
          *(u16*)swzb(OswE, lq, (32 + drow) * 2) = f2bf(o1e[r] * inv);
        }
        u16* dst = Co + ((size_t)(b * S_ + 64 * g + lq)) * EMB_ + h * HS_ + hi * 32;
#pragma unroll
        for (int k = 0; k < 4; ++k) {
          u16x8 vv = *swzp(OswE, lq, (hi * 32 + k * 8) * 2);
          *(u16x8*)(dst + k * 8) = vv;
        }
      }
      {
        float inv = 1.0f / llo;
#pragma unroll
        for (int r = 0; r < 16; ++r) {
          int drow = (r & 3) + 8 * (r >> 2) + 4 * hi;
          *(u16*)swzb(OswO, lq, drow * 2) = f2bf(o0o[r] * inv);
          *(u16*)swzb(OswO, lq, (32 + drow) * 2) = f2bf(o1o[r] * inv);
        }
        u16* dst = Co + ((size_t)(b * S_ + 64 * g + 32 + lq)) * EMB_ + h * HS_ + hi * 32;
#pragma unroll
        for (int k = 0; k < 4; ++k) {
          u16x8 vv = *swzp(OswO, lq, (hi * 32 + k * 8) * 2);
          *(u16x8*)(dst + k * 8) = vv;
        }
      }
    }
    __syncthreads();   // protect Xch/Osw before next phase
  }
}

// ---------------- K3: out = concat @ Wo + bo (fp32 out), 64x128 tiles ----------------
__global__ __launch_bounds__(256) void k_outproj(
    const u16* __restrict__ Cc, const u16* __restrict__ Wot,
    const float* __restrict__ bo, float* __restrict__ out) {
  __shared__ __align__(16) u16 As[64][64];
  __shared__ __align__(16) u16 Bs[128][64];
  const int bid = blockIdx.x;
  const int xcd = bid & 7, sl = bid >> 3;
  const int mb = (xcd << 3) | (sl >> 3);
  const int nb = sl & 7;
  const int t = threadIdx.x;
  const int lane = t & 63, wv = t >> 6;
  const int lq = lane & 15, lg = lane >> 4;
  const int wr = wv >> 1, wc = wv & 1;
  const int srA = t >> 2, scA = (t & 3) << 4;
  const int srB = t >> 1, scB = (t & 1) << 5;
  f32x4 acc[2][4];
#pragma unroll
  for (int mi = 0; mi < 2; ++mi)
#pragma unroll
    for (int ni = 0; ni < 4; ++ni) { f32x4 z = {0.f, 0.f, 0.f, 0.f}; acc[mi][ni] = z; }
  const u16* abase = Cc + ((size_t)(mb * 64 + srA)) * EMB_ + scA;
  const u16* bbase = Wot + ((size_t)(nb * 128 + srB)) * EMB_ + scB;
  u16x8 ar[2], br[4];
#pragma unroll
  for (int q = 0; q < 2; ++q) ar[q] = *(const u16x8*)(abase + q * 8);
#pragma unroll
  for (int q = 0; q < 4; ++q) br[q] = *(const u16x8*)(bbase + q * 8);
  for (int kt = 0; kt < 16; ++kt) {
    __syncthreads();
#pragma unroll
    for (int q = 0; q < 2; ++q) *swzp(As, srA, (scA + q * 8) * 2) = ar[q];
#pragma unroll
    for (int q = 0; q < 4; ++q) *swzp(Bs, srB, (scB + q * 8) * 2) = br[q];
    __syncthreads();
    if (kt < 15) {
#pragma unroll
      for (int q = 0; q < 2; ++q) ar[q] = *(const u16x8*)(abase + (kt + 1) * 64 + q * 8);
#pragma unroll
      for (int q = 0; q < 4; ++q) br[q] = *(const u16x8*)(bbase + (kt + 1) * 64 + q * 8);
    }
#pragma unroll
    for (int kf = 0; kf < 2; ++kf) {
      u16x8 af[2], bf[4];
#pragma unroll
      for (int mi = 0; mi < 2; ++mi)
        af[mi] = *swzp(As, wr * 32 + mi * 16 + lq, kf * 64 + lg * 16);
#pragma unroll
      for (int ni = 0; ni < 4; ++ni)
        bf[ni] = *swzp(Bs, wc * 64 + ni * 16 + lq, kf * 64 + lg * 16);
#pragma unroll
      for (int mi = 0; mi < 2; ++mi)
#pragma unroll
        for (int ni = 0; ni < 4; ++ni)
          acc[mi][ni] = mfma16(af[mi], bf[ni], acc[mi][ni]);
    }
  }
#pragma unroll
  for (int mi = 0; mi < 2; ++mi) {
#pragma unroll
    for (int ni = 0; ni < 4; ++ni) {
      int col = nb * 128 + wc * 64 + ni * 16 + lq;
      float bv = bo[col];
#pragma unroll
      for (int rr = 0; rr < 4; ++rr) {
        int row = mb * 64 + wr * 32 + mi * 16 + lg * 4 + rr;
        out[(size_t)row * EMB_ + col] = acc[mi][ni][rr] + bv;
      }
    }
  }
}

extern "C" void kernel_launch(void* const* d_in, const int* in_sizes, int n_in,
                              void* d_out, int out_size, void* d_ws, size_t ws_size,
                              hipStream_t stream) {
  const float* xk = (const float*)d_in[0];
  const float* xv = (const float*)d_in[1];
  const float* xq = (const float*)d_in[2];
  const float* Wk = (const float*)d_in[3];
  const float* Wv = (const float*)d_in[4];
  const float* Wq = (const float*)d_in[5];
  const float* Wo = (const float*)d_in[6];
  const float* bo = (const float*)d_in[7];
  float* out = (float*)d_out;
  char* ws = (char*)d_ws;
  const size_t MB8 = (size_t)8 * 1024 * 1024;
  u16* Qfw = (u16*)(ws);             // fragment-major Q (pre-scaled, exp2 domain)
  u16* Kfw = (u16*)(ws + MB8);       // fragment-major K
  u16* Vfw = (u16*)(ws + 2 * MB8);   // fragment-major V^T
  u16* Cw  = (u16*)(ws + 3 * MB8);   // concat [2][2048][1024]
  u16* Wot = (u16*)(ws + 4 * MB8);   // [1024][1024]

  k_transpose_wo<<<dim3(16, 16), 256, 0, stream>>>(Wo, Wot);
  k_proj<<<dim3(32, 32, 3), 256, 0, stream>>>(xq, xk, xv, Wq, Wk, Wv, Qfw, Kfw, Vfw);
  k_attn<<<512, 256, 0, stream>>>(Qfw, Kfw, Vfw, Cw);
  k_outproj<<<512, 256, 0, stream>>>(Cw, Wot, bo, out);
}

// Round 12
// 64.840 us; speedup vs baseline: 1.0748x; 1.0188x over previous
//
#include <hip/hip_runtime.h>
#include <hip/hip_bf16.h>
#include <cstdint>

typedef unsigned short u16;
typedef __bf16 bf16x8 __attribute__((ext_vector_type(8)));
typedef u16 u16x8 __attribute__((ext_vector_type(8)));
typedef unsigned u32x4 __attribute__((ext_vector_type(4)));
typedef float f32x2 __attribute__((ext_vector_type(2)));
typedef float f32x4 __attribute__((ext_vector_type(4)));
typedef float f32x16 __attribute__((ext_vector_type(16)));

#define B_ 2
#define S_ 2048
#define H_ 16
#define HS_ 64
#define EMB_ 1024
#define QSCALE 0.022097086912079608f  /* 1/sqrt(2048) */
#define LOG2E  1.4426950408889634f    /* folded into Q so softmax uses exp2 */

static __device__ __forceinline__ u16 f2bf(float f) {
  unsigned int u = __float_as_uint(f);
  u += 0x7fffu + ((u >> 16) & 1u);   // RNE
  return (u16)(u >> 16);
}

// single-instruction 2^x
static __device__ __forceinline__ float ex2(float x) {
#if __has_builtin(__builtin_amdgcn_exp2f)
  return __builtin_amdgcn_exp2f(x);
#else
  float r; asm("v_exp_f32 %0, %1" : "=v"(r) : "v"(x)); return r;
#endif
}

// depth-4 tree sum of 16 floats
static __device__ __forceinline__ float tsum16(const f32x16& s) {
  float a0 = s[0] + s[1],  a1 = s[2] + s[3];
  float a2 = s[4] + s[5],  a3 = s[6] + s[7];
  float a4 = s[8] + s[9],  a5 = s[10] + s[11];
  float a6 = s[12] + s[13], a7 = s[14] + s[15];
  a0 += a1; a2 += a3; a4 += a5; a6 += a7;
  a0 += a2; a4 += a6;
  return a0 + a4;
}

static __device__ __forceinline__ f32x4 mfma16(u16x8 a, u16x8 b, f32x4 c) {
  return __builtin_amdgcn_mfma_f32_16x16x32_bf16(
      __builtin_bit_cast(bf16x8, a), __builtin_bit_cast(bf16x8, b), c, 0, 0, 0);
}
static __device__ __forceinline__ f32x16 mfma32(u16x8 a, u16x8 b, f32x16 c) {
  return __builtin_amdgcn_mfma_f32_32x32x16_bf16(
      __builtin_bit_cast(bf16x8, a), __builtin_bit_cast(bf16x8, b), c, 0, 0, 0);
}

// XOR-swizzled address into a tile with 128B row stride (LDS bank-conflict fix).
static __device__ __forceinline__ char* swzb(void* base, int row, int colbyte) {
  return (char*)base + ((row * 128 + colbyte) ^ ((row & 7) << 4));
}
static __device__ __forceinline__ u16x8* swzp(void* base, int row, int colbyte) {
  return (u16x8*)swzb(base, row, colbyte);
}

// cvt_pk two f32 pairs to packed bf16 words, then permlane32_swap (T12).
static __device__ __forceinline__ void pk_swap(float a0, float a1, float b0, float b1,
                                               unsigned& x, unsigned& y) {
  unsigned A, Bv;
  asm("v_cvt_pk_bf16_f32 %0, %1, %2" : "=v"(A) : "v"(a0), "v"(a1));
  asm("v_cvt_pk_bf16_f32 %0, %1, %2" : "=v"(Bv) : "v"(b0), "v"(b1));
  asm("v_permlane32_swap_b32 %0, %1" : "+v"(A), "+v"(Bv));
  x = A; y = Bv;
}

// P (16 f32 = one 32-kv half-tile for one q-tile) -> two PV B-fragments
static __device__ __forceinline__ void pack2(const f32x16& s0, u16x8& pf0, u16x8& pf1) {
  unsigned w0, w1, w2, w3;
  pk_swap(s0[0], s0[1], s0[4], s0[5], w0, w2);
  pk_swap(s0[2], s0[3], s0[6], s0[7], w1, w3);
  pf0 = __builtin_bit_cast(u16x8, (u32x4){w0, w1, w2, w3});
  pk_swap(s0[8], s0[9], s0[12], s0[13], w0, w2);
  pk_swap(s0[10], s0[11], s0[14], s0[15], w1, w3);
  pf1 = __builtin_bit_cast(u16x8, (u32x4){w0, w1, w2, w3});
}

// ---------------- K0: Wo[k][n] fp32 -> Wot[n][k] bf16 ----------------
__global__ __launch_bounds__(256) void k_transpose_wo(const float* __restrict__ Wo,
                                                      u16* __restrict__ Wot) {
  __shared__ __align__(16) u16 T[64][72];
  const int kb = blockIdx.y * 64, nb = blockIdx.x * 64;
  const int r = threadIdx.x >> 2;
  const int c0 = (threadIdx.x & 3) << 4;
  const float* src = Wo + (size_t)(kb + r) * EMB_ + nb + c0;
#pragma unroll
  for (int i = 0; i < 16; i += 4) {
    float4 f = *(const float4*)(src + i);
    T[c0 + i + 0][r] = f2bf(f.x);
    T[c0 + i + 1][r] = f2bf(f.y);
    T[c0 + i + 2][r] = f2bf(f.z);
    T[c0 + i + 3][r] = f2bf(f.w);
  }
  __syncthreads();
  u16* dst = Wot + (size_t)(nb + r) * EMB_ + kb + c0;
  *(u16x8*)(dst)     = *(const u16x8*)&T[r][c0];
  *(u16x8*)(dst + 8) = *(const u16x8*)&T[r][c0 + 8];
}

// ---------------- K1: projections -> FRAGMENT-MAJOR layouts (tn = blockIdx.z) ----
// Qf: [bh][t:64][slice:4][lane:64][8]   = Q[t*32+(l&31)][slice*16+(l>>5)*8+j] * QSCALE*LOG2E
// Kf: [bh][tau:64][slice:4][lane:64][8] = K[tau*32+(l&31)][slice*16+(l>>5)*8+j]
// Vf: [bh][j:32][eta:2][kap:4][lane:64][8] = Vt[eta*32+(l&31)][j*64+kap*16+(l>>5)*8+jj]
__global__ __launch_bounds__(256) void k_proj(
    const float* __restrict__ xq, const float* __restrict__ xk, const float* __restrict__ xv,
    const float* __restrict__ Wq, const float* __restrict__ Wk, const float* __restrict__ Wv,
    u16* __restrict__ Qf, u16* __restrict__ Kf, u16* __restrict__ Vf) {
  __shared__ __align__(16) u16 Xb[64][64];
  __shared__ __align__(16) u16 Wb[64][64];   // Wb[e][d] = W[d][e]
  __shared__ __align__(16) u16 Tt[64][64];
  const int sb = blockIdx.x;   // s-block 0..31
  const int bh = blockIdx.y;   // 0..31
  const int tn = blockIdx.z;   // 0=Q, 1=K, 2=V
  const int b = bh >> 4, h = bh & 15;
  const int t = threadIdx.x;
  const int r = t >> 2, c0 = (t & 3) << 4;
  const int lane = t & 63, wv = t >> 6;
  const int lq = lane & 15, lg = lane >> 4;
  const int l31 = lane & 31, hi = lane >> 5;
  const float* xs = (tn == 0) ? xq : (tn == 1) ? xk : xv;
  const float* wsp3 = (tn == 0) ? Wq : (tn == 1) ? Wk : Wv;

  const float* src = xs + ((size_t)(b * S_ + sb * 64 + r)) * HS_ + c0;
#pragma unroll
  for (int i = 0; i < 16; i += 8) {
    float4 fa = *(const float4*)(src + i);
    float4 fb = *(const float4*)(src + i + 4);
    u16x8 v = {f2bf(fa.x), f2bf(fa.y), f2bf(fa.z), f2bf(fa.w),
               f2bf(fb.x), f2bf(fb.y), f2bf(fb.z), f2bf(fb.w)};
    *swzp(Xb, r, (c0 + i) * 2) = v;
  }
  const float* wsp = wsp3 + ((size_t)(h * HS_ + r)) * HS_ + c0;
#pragma unroll
  for (int i = 0; i < 16; i += 4) {
    float4 f = *(const float4*)(wsp + i);
    *(u16*)swzb(Wb, c0 + i + 0, r * 2) = f2bf(f.x);
    *(u16*)swzb(Wb, c0 + i + 1, r * 2) = f2bf(f.y);
    *(u16*)swzb(Wb, c0 + i + 2, r * 2) = f2bf(f.z);
    *(u16*)swzb(Wb, c0 + i + 3, r * 2) = f2bf(f.w);
  }
  __syncthreads();
  if (tn < 2) {
    u16x8 a0 = *swzp(Xb, wv * 16 + lq, lg * 16);
    u16x8 a1 = *swzp(Xb, wv * 16 + lq, 64 + lg * 16);
    const float osc = (tn == 0) ? (QSCALE * LOG2E) : 1.0f;
#pragma unroll
    for (int et = 0; et < 4; ++et) {
      u16x8 b0 = *swzp(Wb, et * 16 + lq, lg * 16);
      u16x8 b1 = *swzp(Wb, et * 16 + lq, 64 + lg * 16);
      f32x4 acc = {0.f, 0.f, 0.f, 0.f};
      acc = mfma16(a0, b0, acc);
      acc = mfma16(a1, b1, acc);
#pragma unroll
      for (int rr = 0; rr < 4; ++rr)
        *(u16*)swzb(Tt, wv * 16 + lg * 4 + rr, (et * 16 + lq) * 2) = f2bf(acc[rr] * osc);
    }
  } else {
    u16x8 xb0 = *swzp(Xb, wv * 16 + lq, lg * 16);
    u16x8 xb1 = *swzp(Xb, wv * 16 + lq, 64 + lg * 16);
#pragma unroll
    for (int et = 0; et < 4; ++et) {
      u16x8 a0 = *swzp(Wb, et * 16 + lq, lg * 16);
      u16x8 a1 = *swzp(Wb, et * 16 + lq, 64 + lg * 16);
      f32x4 acc = {0.f, 0.f, 0.f, 0.f};
      acc = mfma16(a0, xb0, acc);
      acc = mfma16(a1, xb1, acc);
#pragma unroll
      for (int rr = 0; rr < 4; ++rr)
        *(u16*)swzb(Tt, et * 16 + lg * 4 + rr, (wv * 16 + lq) * 2) = f2bf(acc[rr]);
    }
  }
  __syncthreads();
  if (tn < 2) {
    u16* dst = (tn == 0) ? Qf : Kf;
#pragma unroll
    for (int tl = 0; tl < 2; ++tl) {
      u16x8 v = *swzp(Tt, tl * 32 + l31, wv * 32 + hi * 16);
      size_t off = (((size_t)(bh * 64 + sb * 2 + tl)) * 4 + wv) * 512 + lane * 8;
      *(u16x8*)(dst + off) = v;
    }
  } else {
#pragma unroll
    for (int eta = 0; eta < 2; ++eta) {
      u16x8 v = *swzp(Tt, eta * 32 + l31, wv * 32 + hi * 16);
      size_t off = ((((size_t)(bh * 32 + sb)) * 2 + eta) * 4 + wv) * 512 + lane * 8;
      *(u16x8*)(Vf + off) = v;
    }
  }
}

// ---------------- K2: causal flash attention, 64 q-rows/wave, 32-kv steps ----------
// R9 structure verbatim (known-good): 4-wave kv-quarter split, diag peeled with its
// own kf2/vf2 buffers, single-round 3-slice merge, launch_bounds(256,2).
__global__ __launch_bounds__(256, 2) void k_attn(
    const u16* __restrict__ Qf, const u16* __restrict__ Kf, const u16* __restrict__ Vf,
    u16* __restrict__ Co) {
  __shared__ float Xch[3][64][66];               // waves 1-3 partials
  __shared__ __align__(16) u16 OswE[32][64];
  __shared__ __align__(16) u16 OswO[32][64];
  const int bid = blockIdx.x;
  const int xcd = bid & 7, idx = bid >> 3;
  const int bh = (xcd << 2) | (idx & 3);
  const int p = idx >> 2;                        // 0..15
  const int b = bh >> 4, h = bh & 15;
  const int w = threadIdx.x >> 6;                // wave 0..3
  const int l = threadIdx.x & 63;
  const int lq = l & 31, hi = l >> 5;
  const float NEG = -3.0e38f;

  const u16* Kbase = Kf + ((size_t)(bh * 64) * 4) * 512 + l * 8;   // per 32-kv tau
  const u16* Vbase = Vf + ((size_t)(bh * 32) * 8) * 512 + l * 8;   // per 64-kv j

#pragma unroll 1
  for (int ph = 0; ph < 2; ++ph) {
    const int g = ph ? (31 - p) : p;
    const int n = g + 1;                         // 64-kv tiles needed
    const int js = (w * n) >> 2;
    const int je = ((w + 1) * n) >> 2;
    const bool dw = (w == 3);                    // diag owner
    const int t32s = 2 * js;
    const int t32e = dw ? 2 * (n - 1) : 2 * je;  // 32-kv loop end (diag excluded)
    const int tlim = dw ? t32e + 1 : t32e;       // prefetch validity bound

    const u16* Qe = Qf + (((size_t)(bh * 64 + 2 * g)) * 4) * 512 + l * 8;
    u16x8 qfe[4], qfo[4];
#pragma unroll
    for (int ss = 0; ss < 4; ++ss) {
      qfe[ss] = *(const u16x8*)(Qe + ss * 512);
      qfo[ss] = *(const u16x8*)(Qe + (4 + ss) * 512);
    }

    f32x16 o0e, o1e, o0o, o1o;
#pragma unroll
    for (int r = 0; r < 16; ++r) { o0e[r] = 0.f; o1e[r] = 0.f; o0o[r] = 0.f; o1o[r] = 0.f; }
    float lle = 0.f, llo = 0.f;

    u16x8 kf4[4], vf4[4];
    const bool havework = dw || (js < je);
    if (havework) {  // prologue: first 32-kv step's K and V
      const u16* pk = Kbase + ((size_t)t32s * 4) * 512;
      size_t vb = ((size_t)(t32s >> 1) * 8 + (size_t)(t32s & 1) * 2);
#pragma unroll
      for (int ss = 0; ss < 4; ++ss) kf4[ss] = *(const u16x8*)(pk + ss * 512);
      vf4[0] = *(const u16x8*)(Vbase + (vb + 0) * 512);
      vf4[1] = *(const u16x8*)(Vbase + (vb + 1) * 512);
      vf4[2] = *(const u16x8*)(Vbase + (vb + 4) * 512);
      vf4[3] = *(const u16x8*)(Vbase + (vb + 5) * 512);
    }

    for (int t32 = t32s; t32 < t32e; ++t32) {
      const bool pre = (t32 + 1 < tlim);
      u16x8 pfA, pfB;
      f32x16 s;
      // ---- even q-tile ----
#pragma unroll
      for (int r = 0; r < 16; ++r) s[r] = -16.f;
      __builtin_amdgcn_s_setprio(1);
      s = mfma32(kf4[0], qfe[0], s);
      s = mfma32(kf4[1], qfe[1], s);
      s = mfma32(kf4[2], qfe[2], s);
      s = mfma32(kf4[3], qfe[3], s);
      __builtin_amdgcn_s_setprio(0);
#pragma unroll
      for (int r = 0; r < 16; ++r) s[r] = ex2(s[r]);
      lle += tsum16(s);
      pack2(s, pfA, pfB);
      __builtin_amdgcn_s_setprio(1);
      o0e = mfma32(vf4[0], pfA, o0e);
      o0e = mfma32(vf4[1], pfB, o0e);
      o1e = mfma32(vf4[2], pfA, o1e);
      o1e = mfma32(vf4[3], pfB, o1e);
      __builtin_amdgcn_s_setprio(0);
      // ---- odd q-tile (K dies after these issue) ----
#pragma unroll
      for (int r = 0; r < 16; ++r) s[r] = -16.f;
      __builtin_amdgcn_s_setprio(1);
      s = mfma32(kf4[0], qfo[0], s);
      s = mfma32(kf4[1], qfo[1], s);
      s = mfma32(kf4[2], qfo[2], s);
      s = mfma32(kf4[3], qfo[3], s);
      __builtin_amdgcn_s_setprio(0);
      if (pre) {  // in-place K prefetch
        const u16* pk = Kbase + ((size_t)(t32 + 1) * 4) * 512;
#pragma unroll
        for (int ss = 0; ss < 4; ++ss) kf4[ss] = *(const u16x8*)(pk + ss * 512);
      }
#pragma unroll
      for (int r = 0; r < 16; ++r) s[r] = ex2(s[r]);
      llo += tsum16(s);
      pack2(s, pfA, pfB);
      __builtin_amdgcn_s_setprio(1);
      o0o = mfma32(vf4[0], pfA, o0o);
      o0o = mfma32(vf4[1], pfB, o0o);
      o1o = mfma32(vf4[2], pfA, o1o);
      o1o = mfma32(vf4[3], pfB, o1o);
      __builtin_amdgcn_s_setprio(0);
      if (pre) {  // in-place V prefetch
        size_t vb = ((size_t)((t32 + 1) >> 1) * 8 + (size_t)((t32 + 1) & 1) * 2);
        vf4[0] = *(const u16x8*)(Vbase + (vb + 0) * 512);
        vf4[1] = *(const u16x8*)(Vbase + (vb + 1) * 512);
        vf4[2] = *(const u16x8*)(Vbase + (vb + 4) * 512);
        vf4[3] = *(const u16x8*)(Vbase + (vb + 5) * 512);
      }
    }

    if (dw) {  // peeled diagonal 64-kv tile: d0 = low 32 kv, d1 = high 32 kv
      // load d1's K/V into a second small buffer NOW (hides under d0 compute)
      u16x8 kf2[4], vf2[4];
      {
        const int t1 = 2 * n - 1;
        const u16* pk = Kbase + ((size_t)t1 * 4) * 512;
        size_t vb = ((size_t)(t1 >> 1) * 8 + (size_t)(t1 & 1) * 2);
#pragma unroll
        for (int ss = 0; ss < 4; ++ss) kf2[ss] = *(const u16x8*)(pk + ss * 512);
        vf2[0] = *(const u16x8*)(Vbase + (vb + 0) * 512);
        vf2[1] = *(const u16x8*)(Vbase + (vb + 1) * 512);
        vf2[2] = *(const u16x8*)(Vbase + (vb + 4) * 512);
        vf2[3] = *(const u16x8*)(Vbase + (vb + 5) * 512);
      }
      u16x8 pfA, pfB;
      f32x16 s;
      // d0, even tile: triangular mask (crow > lq)
#pragma unroll
      for (int r = 0; r < 16; ++r) s[r] = -16.f;
      s = mfma32(kf4[0], qfe[0], s);
      s = mfma32(kf4[1], qfe[1], s);
      s = mfma32(kf4[2], qfe[2], s);
      s = mfma32(kf4[3], qfe[3], s);
#pragma unroll
      for (int r = 0; r < 16; ++r) {
        int crow = (r & 3) + 8 * (r >> 2) + 4 * hi;
        if (crow > lq) s[r] = NEG;
      }
#pragma unroll
      for (int r = 0; r < 16; ++r) s[r] = ex2(s[r]);
      lle += tsum16(s);
      pack2(s, pfA, pfB);
      o0e = mfma32(vf4[0], pfA, o0e);
      o0e = mfma32(vf4[1], pfB, o0e);
      o1e = mfma32(vf4[2], pfA, o1e);
      o1e = mfma32(vf4[3], pfB, o1e);
      // d0, odd tile: fully visible
#pragma unroll
      for (int r = 0; r < 16; ++r) s[r] = -16.f;
      s = mfma32(kf4[0], qfo[0], s);
      s = mfma32(kf4[1], qfo[1], s);
      s = mfma32(kf4[2], qfo[2], s);
      s = mfma32(kf4[3], qfo[3], s);
#pragma unroll
      for (int r = 0; r < 16; ++r) s[r] = ex2(s[r]);
      llo += tsum16(s);
      pack2(s, pfA, pfB);
      o0o = mfma32(vf4[0], pfA, o0o);
      o0o = mfma32(vf4[1], pfB, o0o);
      o1o = mfma32(vf4[2], pfA, o1o);
      o1o = mfma32(vf4[3], pfB, o1o);
      // d1, odd tile only: triangular mask (crow > lq); even tile fully masked
#pragma unroll
      for (int r = 0; r < 16; ++r) s[r] = -16.f;
      s = mfma32(kf2[0], qfo[0], s);
      s = mfma32(kf2[1], qfo[1], s);
      s = mfma32(kf2[2], qfo[2], s);
      s = mfma32(kf2[3], qfo[3], s);
#pragma unroll
      for (int r = 0; r < 16; ++r) {
        int crow = (r & 3) + 8 * (r >> 2) + 4 * hi;
        if (crow > lq) s[r] = NEG;
      }
#pragma unroll
      for (int r = 0; r < 16; ++r) s[r] = ex2(s[r]);
      llo += tsum16(s);
      pack2(s, pfA, pfB);
      o0o = mfma32(vf2[0], pfA, o0o);
      o0o = mfma32(vf2[1], pfB, o0o);
      o1o = mfma32(vf2[2], pfA, o1o);
      o1o = mfma32(vf2[3], pfB, o1o);
    }

    // ---- single-round 3-slice merge (pure sums) ----
    if (w) {
      f32x2* xr = (f32x2*)(&Xch[w - 1][l][0]);
#pragma unroll
      for (int i = 0; i < 8; ++i) {
        xr[i]      = (f32x2){o0e[2 * i], o0e[2 * i + 1]};
        xr[8 + i]  = (f32x2){o1e[2 * i], o1e[2 * i + 1]};
        xr[16 + i] = (f32x2){o0o[2 * i], o0o[2 * i + 1]};
        xr[24 + i] = (f32x2){o1o[2 * i], o1o[2 * i + 1]};
      }
      xr[32] = (f32x2){lle, llo};
    }
    __syncthreads();
    if (w == 0) {
#pragma unroll
      for (int wv = 0; wv < 3; ++wv) {
        const f32x2* xr = (const f32x2*)(&Xch[wv][l][0]);
#pragma unroll
        for (int i = 0; i < 8; ++i) {
          f32x2 a = xr[i], bq = xr[8 + i], c = xr[16 + i], d = xr[24 + i];
          o0e[2 * i] += a[0]; o0e[2 * i + 1] += a[1];
          o1e[2 * i] += bq[0]; o1e[2 * i + 1] += bq[1];
          o0o[2 * i] += c[0]; o0o[2 * i + 1] += c[1];
          o1o[2 * i] += d[0]; o1o[2 * i + 1] += d[1];
        }
        f32x2 e = xr[32];
        lle += e[0]; llo += e[1];
      }
      lle += __shfl_xor(lle, 32);
      llo += __shfl_xor(llo, 32);
      {
        float inv = 1.0f / lle;
#pragma unroll
        for (int r = 0; r < 16; ++r) {
          int drow = (r & 3) + 8 * (r >> 2) + 4 * hi;
          *(u16*)swzb(OswE, lq, drow * 2) = f2bf(o0e[r] * inv);
          *(u16*)swzb(OswE, lq, (32 + drow) * 2) = f2bf(o1e[r] * inv);
        }
        u16* dst = Co + ((size_t)(b * S_ + 64 * g + lq)) * EMB_ + h * HS_ + hi * 32;
#pragma unroll
        for (int k = 0; k < 4; ++k) {
          u16x8 vv = *swzp(OswE, lq, (hi * 32 + k * 8) * 2);
          *(u16x8*)(dst + k * 8) = vv;
        }
      }
      {
        float inv = 1.0f / llo;
#pragma unroll
        for (int r = 0; r < 16; ++r) {
          int drow = (r & 3) + 8 * (r >> 2) + 4 * hi;
          *(u16*)swzb(OswO, lq, drow * 2) = f2bf(o0o[r] * inv);
          *(u16*)swzb(OswO, lq, (32 + drow) * 2) = f2bf(o1o[r] * inv);
        }
        u16* dst = Co + ((size_t)(b * S_ + 64 * g + 32 + lq)) * EMB_ + h * HS_ + hi * 32;
#pragma unroll
        for (int k = 0; k < 4; ++k) {
          u16x8 vv = *swzp(OswO, lq, (hi * 32 + k * 8) * 2);
          *(u16x8*)(dst + k * 8) = vv;
        }
      }
    }
    __syncthreads();   // protect Xch/Osw before next phase
  }
}

// ---------------- K3: out = concat @ Wo + bo (fp32 out), 64x128 tiles --------------
// R12 delta: staging via global_load_lds (width 16). LDS dest is LINEAR (gload_lds
// writes base+lane*16); global source is PRE-SWIZZLED (chunk' = (l&7)^(l>>3), same
// 128B line so still coalesced); fragment reads keep the same XOR swizzle (rule #21).
__global__ __launch_bounds__(256) void k_outproj(
    const u16* __restrict__ Cc, const u16* __restrict__ Wot,
    const float* __restrict__ bo, float* __restrict__ out) {
  __shared__ __align__(16) u16 As[64][64];
  __shared__ __align__(16) u16 Bs[128][64];
  const int bid = blockIdx.x;
  const int xcd = bid & 7, sl = bid >> 3;
  const int mb = (xcd << 3) | (sl >> 3);
  const int nb = sl & 7;
  const int t = threadIdx.x;
  const int lane = t & 63, wv = t >> 6;
  const int lq = lane & 15, lg = lane >> 4;
  const int wr = wv >> 1, wc = wv & 1;
  const int lrow = lane >> 3;                       // row within 8-row group
  const int lchk = ((lane & 7) ^ (lane >> 3)) * 8;  // pre-swizzled u16 col offset
  f32x4 acc[2][4];
#pragma unroll
  for (int mi = 0; mi < 2; ++mi)
#pragma unroll
    for (int ni = 0; ni < 4; ++ni) { f32x4 z = {0.f, 0.f, 0.f, 0.f}; acc[mi][ni] = z; }
  // per-lane global bases (row part fixed, col advances by kt*64)
  const u16* ga0 = Cc + (size_t)(mb * 64 + wv * 16 + lrow) * EMB_ + lchk;
  const u16* ga1 = Cc + (size_t)(mb * 64 + wv * 16 + 8 + lrow) * EMB_ + lchk;
  const u16* gb0 = Wot + (size_t)(nb * 128 + wv * 32 + lrow) * EMB_ + lchk;
  const u16* gb1 = Wot + (size_t)(nb * 128 + wv * 32 + 8 + lrow) * EMB_ + lchk;
  const u16* gb2 = Wot + (size_t)(nb * 128 + wv * 32 + 16 + lrow) * EMB_ + lchk;
  const u16* gb3 = Wot + (size_t)(nb * 128 + wv * 32 + 24 + lrow) * EMB_ + lchk;
  typedef __attribute__((address_space(3))) void lds_v;
  typedef const __attribute__((address_space(1))) void glb_v;
  for (int kt = 0; kt < 16; ++kt) {
    __syncthreads();   // previous tile's reads done
    const int co = kt * 64;
    __builtin_amdgcn_global_load_lds((glb_v*)(ga0 + co), (lds_v*)&As[wv * 16][0], 16, 0, 0);
    __builtin_amdgcn_global_load_lds((glb_v*)(ga1 + co), (lds_v*)&As[wv * 16 + 8][0], 16, 0, 0);
    __builtin_amdgcn_global_load_lds((glb_v*)(gb0 + co), (lds_v*)&Bs[wv * 32][0], 16, 0, 0);
    __builtin_amdgcn_global_load_lds((glb_v*)(gb1 + co), (lds_v*)&Bs[wv * 32 + 8][0], 16, 0, 0);
    __builtin_amdgcn_global_load_lds((glb_v*)(gb2 + co), (lds_v*)&Bs[wv * 32 + 16][0], 16, 0, 0);
    __builtin_amdgcn_global_load_lds((glb_v*)(gb3 + co), (lds_v*)&Bs[wv * 32 + 24][0], 16, 0, 0);
    __syncthreads();   // drains vmcnt (compiler emits waitcnt before barrier)
#pragma unroll
    for (int kf = 0; kf < 2; ++kf) {
      u16x8 af[2], bf[4];
#pragma unroll
      for (int mi = 0; mi < 2; ++mi)
        af[mi] = *swzp(As, wr * 32 + mi * 16 + lq, kf * 64 + lg * 16);
#pragma unroll
      for (int ni = 0; ni < 4; ++ni)
        bf[ni] = *swzp(Bs, wc * 64 + ni * 16 + lq, kf * 64 + lg * 16);
#pragma unroll
      for (int mi = 0; mi < 2; ++mi)
#pragma unroll
        for (int ni = 0; ni < 4; ++ni)
          acc[mi][ni] = mfma16(af[mi], bf[ni], acc[mi][ni]);
    }
  }
#pragma unroll
  for (int mi = 0; mi < 2; ++mi) {
#pragma unroll
    for (int ni = 0; ni < 4; ++ni) {
      int col = nb * 128 + wc * 64 + ni * 16 + lq;
      float bv = bo[col];
#pragma unroll
      for (int rr = 0; rr < 4; ++rr) {
        int row = mb * 64 + wr * 32 + mi * 16 + lg * 4 + rr;
        out[(size_t)row * EMB_ + col] = acc[mi][ni][rr] + bv;
      }
    }
  }
}

extern "C" void kernel_launch(void* const* d_in, const int* in_sizes, int n_in,
                              void* d_out, int out_size, void* d_ws, size_t ws_size,
                              hipStream_t stream) {
  const float* xk = (const float*)d_in[0];
  const float* xv = (const float*)d_in[1];
  const float* xq = (const float*)d_in[2];
  const float* Wk = (const float*)d_in[3];
  const float* Wv = (const float*)d_in[4];
  const float* Wq = (const float*)d_in[5];
  const float* Wo = (const float*)d_in[6];
  const float* bo = (const float*)d_in[7];
  float* out = (float*)d_out;
  char* ws = (char*)d_ws;
  const size_t MB8 = (size_t)8 * 1024 * 1024;
  u16* Qfw = (u16*)(ws);             // fragment-major Q (pre-scaled, exp2 domain)
  u16* Kfw = (u16*)(ws + MB8);       // fragment-major K
  u16* Vfw = (u16*)(ws + 2 * MB8);   // fragment-major V^T
  u16* Cw  = (u16*)(ws + 3 * MB8);   // concat [2][2048][1024]
  u16* Wot = (u16*)(ws + 4 * MB8);   // [1024][1024]

  k_transpose_wo<<<dim3(16, 16), 256, 0, stream>>>(Wo, Wot);
  k_proj<<<dim3(32, 32, 3), 256, 0, stream>>>(xq, xk, xv, Wq, Wk, Wv, Qfw, Kfw, Vfw);
  k_attn<<<512, 256, 0, stream>>>(Qfw, Kfw, Vfw, Cw);
  k_outproj<<<512, 256, 0, stream>>>(Cw, Wot, bo, out);
}

// Round 14
// 64.400 us; speedup vs baseline: 1.0821x; 1.0068x over previous
//
#include <hip/hip_runtime.h>
#include <hip/hip_bf16.h>
#include <cstdint>

typedef unsigned short u16;
typedef __bf16 bf16x8 __attribute__((ext_vector_type(8)));
typedef u16 u16x8 __attribute__((ext_vector_type(8)));
typedef unsigned u32x4 __attribute__((ext_vector_type(4)));
typedef float f32x2 __attribute__((ext_vector_type(2)));
typedef float f32x4 __attribute__((ext_vector_type(4)));
typedef float f32x16 __attribute__((ext_vector_type(16)));

#define B_ 2
#define S_ 2048
#define H_ 16
#define HS_ 64
#define EMB_ 1024
#define QSCALE 0.022097086912079608f  /* 1/sqrt(2048) */
#define LOG2E  1.4426950408889634f    /* folded into Q so softmax uses exp2 */

static __device__ __forceinline__ u16 f2bf(float f) {
  unsigned int u = __float_as_uint(f);
  u += 0x7fffu + ((u >> 16) & 1u);   // RNE
  return (u16)(u >> 16);
}

// single-instruction 2^x
static __device__ __forceinline__ float ex2(float x) {
#if __has_builtin(__builtin_amdgcn_exp2f)
  return __builtin_amdgcn_exp2f(x);
#else
  float r; asm("v_exp_f32 %0, %1" : "=v"(r) : "v"(x)); return r;
#endif
}

// depth-4 tree sum of 16 floats
static __device__ __forceinline__ float tsum16(const f32x16& s) {
  float a0 = s[0] + s[1],  a1 = s[2] + s[3];
  float a2 = s[4] + s[5],  a3 = s[6] + s[7];
  float a4 = s[8] + s[9],  a5 = s[10] + s[11];
  float a6 = s[12] + s[13], a7 = s[14] + s[15];
  a0 += a1; a2 += a3; a4 += a5; a6 += a7;
  a0 += a2; a4 += a6;
  return a0 + a4;
}

static __device__ __forceinline__ f32x4 mfma16(u16x8 a, u16x8 b, f32x4 c) {
  return __builtin_amdgcn_mfma_f32_16x16x32_bf16(
      __builtin_bit_cast(bf16x8, a), __builtin_bit_cast(bf16x8, b), c, 0, 0, 0);
}
static __device__ __forceinline__ f32x16 mfma32(u16x8 a, u16x8 b, f32x16 c) {
  return __builtin_amdgcn_mfma_f32_32x32x16_bf16(
      __builtin_bit_cast(bf16x8, a), __builtin_bit_cast(bf16x8, b), c, 0, 0, 0);
}

// XOR-swizzled address into a tile with 128B row stride (LDS bank-conflict fix).
static __device__ __forceinline__ char* swzb(void* base, int row, int colbyte) {
  return (char*)base + ((row * 128 + colbyte) ^ ((row & 7) << 4));
}
static __device__ __forceinline__ u16x8* swzp(void* base, int row, int colbyte) {
  return (u16x8*)swzb(base, row, colbyte);
}

// cvt_pk two f32 pairs to packed bf16 words, then permlane32_swap (T12).
static __device__ __forceinline__ void pk_swap(float a0, float a1, float b0, float b1,
                                               unsigned& x, unsigned& y) {
  unsigned A, Bv;
  asm("v_cvt_pk_bf16_f32 %0, %1, %2" : "=v"(A) : "v"(a0), "v"(a1));
  asm("v_cvt_pk_bf16_f32 %0, %1, %2" : "=v"(Bv) : "v"(b0), "v"(b1));
  asm("v_permlane32_swap_b32 %0, %1" : "+v"(A), "+v"(Bv));
  x = A; y = Bv;
}

// P (16 f32 = one 32-kv half-tile for one q-tile) -> two PV B-fragments
static __device__ __forceinline__ void pack2(const f32x16& s0, u16x8& pf0, u16x8& pf1) {
  unsigned w0, w1, w2, w3;
  pk_swap(s0[0], s0[1], s0[4], s0[5], w0, w2);
  pk_swap(s0[2], s0[3], s0[6], s0[7], w1, w3);
  pf0 = __builtin_bit_cast(u16x8, (u32x4){w0, w1, w2, w3});
  pk_swap(s0[8], s0[9], s0[12], s0[13], w0, w2);
  pk_swap(s0[10], s0[11], s0[14], s0[15], w1, w3);
  pf1 = __builtin_bit_cast(u16x8, (u32x4){w0, w1, w2, w3});
}

// ---------------- K0: Wo[k][n] fp32 -> Wot[n][k] bf16 ----------------
__global__ __launch_bounds__(256) void k_transpose_wo(const float* __restrict__ Wo,
                                                      u16* __restrict__ Wot) {
  __shared__ __align__(16) u16 T[64][72];
  const int kb = blockIdx.y * 64, nb = blockIdx.x * 64;
  const int r = threadIdx.x >> 2;
  const int c0 = (threadIdx.x & 3) << 4;
  const float* src = Wo + (size_t)(kb + r) * EMB_ + nb + c0;
#pragma unroll
  for (int i = 0; i < 16; i += 4) {
    float4 f = *(const float4*)(src + i);
    T[c0 + i + 0][r] = f2bf(f.x);
    T[c0 + i + 1][r] = f2bf(f.y);
    T[c0 + i + 2][r] = f2bf(f.z);
    T[c0 + i + 3][r] = f2bf(f.w);
  }
  __syncthreads();
  u16* dst = Wot + (size_t)(nb + r) * EMB_ + kb + c0;
  *(u16x8*)(dst)     = *(const u16x8*)&T[r][c0];
  *(u16x8*)(dst + 8) = *(const u16x8*)&T[r][c0 + 8];
}

// ---------------- K1: projections -> FRAGMENT-MAJOR layouts (tn = blockIdx.z) ----
// Qf: [bh][t:64][slice:4][lane:64][8]   = Q[t*32+(l&31)][slice*16+(l>>5)*8+j] * QSCALE*LOG2E
// Kf: [bh][tau:64][slice:4][lane:64][8] = K[tau*32+(l&31)][slice*16+(l>>5)*8+j]
// Vf: [bh][j:32][eta:2][kap:4][lane:64][8] = Vt[eta*32+(l&31)][j*64+kap*16+(l>>5)*8+jj]
__global__ __launch_bounds__(256) void k_proj(
    const float* __restrict__ xq, const float* __restrict__ xk, const float* __restrict__ xv,
    const float* __restrict__ Wq, const float* __restrict__ Wk, const float* __restrict__ Wv,
    u16* __restrict__ Qf, u16* __restrict__ Kf, u16* __restrict__ Vf) {
  __shared__ __align__(16) u16 Xb[64][64];
  __shared__ __align__(16) u16 Wb[64][64];   // Wb[e][d] = W[d][e]
  __shared__ __align__(16) u16 Tt[64][64];
  const int sb = blockIdx.x;   // s-block 0..31
  const int bh = blockIdx.y;   // 0..31
  const int tn = blockIdx.z;   // 0=Q, 1=K, 2=V
  const int b = bh >> 4, h = bh & 15;
  const int t = threadIdx.x;
  const int r = t >> 2, c0 = (t & 3) << 4;
  const int lane = t & 63, wv = t >> 6;
  const int lq = lane & 15, lg = lane >> 4;
  const int l31 = lane & 31, hi = lane >> 5;
  const float* xs = (tn == 0) ? xq : (tn == 1) ? xk : xv;
  const float* wsp3 = (tn == 0) ? Wq : (tn == 1) ? Wk : Wv;

  const float* src = xs + ((size_t)(b * S_ + sb * 64 + r)) * HS_ + c0;
#pragma unroll
  for (int i = 0; i < 16; i += 8) {
    float4 fa = *(const float4*)(src + i);
    float4 fb = *(const float4*)(src + i + 4);
    u16x8 v = {f2bf(fa.x), f2bf(fa.y), f2bf(fa.z), f2bf(fa.w),
               f2bf(fb.x), f2bf(fb.y), f2bf(fb.z), f2bf(fb.w)};
    *swzp(Xb, r, (c0 + i) * 2) = v;
  }
  const float* wsp = wsp3 + ((size_t)(h * HS_ + r)) * HS_ + c0;
#pragma unroll
  for (int i = 0; i < 16; i += 4) {
    float4 f = *(const float4*)(wsp + i);
    *(u16*)swzb(Wb, c0 + i + 0, r * 2) = f2bf(f.x);
    *(u16*)swzb(Wb, c0 + i + 1, r * 2) = f2bf(f.y);
    *(u16*)swzb(Wb, c0 + i + 2, r * 2) = f2bf(f.z);
    *(u16*)swzb(Wb, c0 + i + 3, r * 2) = f2bf(f.w);
  }
  __syncthreads();
  if (tn < 2) {
    u16x8 a0 = *swzp(Xb, wv * 16 + lq, lg * 16);
    u16x8 a1 = *swzp(Xb, wv * 16 + lq, 64 + lg * 16);
    const float osc = (tn == 0) ? (QSCALE * LOG2E) : 1.0f;
#pragma unroll
    for (int et = 0; et < 4; ++et) {
      u16x8 b0 = *swzp(Wb, et * 16 + lq, lg * 16);
      u16x8 b1 = *swzp(Wb, et * 16 + lq, 64 + lg * 16);
      f32x4 acc = {0.f, 0.f, 0.f, 0.f};
      acc = mfma16(a0, b0, acc);
      acc = mfma16(a1, b1, acc);
#pragma unroll
      for (int rr = 0; rr < 4; ++rr)
        *(u16*)swzb(Tt, wv * 16 + lg * 4 + rr, (et * 16 + lq) * 2) = f2bf(acc[rr] * osc);
    }
  } else {
    u16x8 xb0 = *swzp(Xb, wv * 16 + lq, lg * 16);
    u16x8 xb1 = *swzp(Xb, wv * 16 + lq, 64 + lg * 16);
#pragma unroll
    for (int et = 0; et < 4; ++et) {
      u16x8 a0 = *swzp(Wb, et * 16 + lq, lg * 16);
      u16x8 a1 = *swzp(Wb, et * 16 + lq, 64 + lg * 16);
      f32x4 acc = {0.f, 0.f, 0.f, 0.f};
      acc = mfma16(a0, xb0, acc);
      acc = mfma16(a1, xb1, acc);
#pragma unroll
      for (int rr = 0; rr < 4; ++rr)
        *(u16*)swzb(Tt, et * 16 + lg * 4 + rr, (wv * 16 + lq) * 2) = f2bf(acc[rr]);
    }
  }
  __syncthreads();
  if (tn < 2) {
    u16* dst = (tn == 0) ? Qf : Kf;
#pragma unroll
    for (int tl = 0; tl < 2; ++tl) {
      u16x8 v = *swzp(Tt, tl * 32 + l31, wv * 32 + hi * 16);
      size_t off = (((size_t)(bh * 64 + sb * 2 + tl)) * 4 + wv) * 512 + lane * 8;
      *(u16x8*)(dst + off) = v;
    }
  } else {
#pragma unroll
    for (int eta = 0; eta < 2; ++eta) {
      u16x8 v = *swzp(Tt, eta * 32 + l31, wv * 32 + hi * 16);
      size_t off = ((((size_t)(bh * 32 + sb)) * 2 + eta) * 4 + wv) * 512 + lane * 8;
      *(u16x8*)(Vf + off) = v;
    }
  }
}

// ---------------- K2: causal flash attention, 64 q-rows/wave, 32-kv steps ----------
// R12 known-good structure (4-wave kv-quarter split, diag kf2/vf2, single-round
// 3-slice merge, launch_bounds(256,2)). R14 delta: inner-step DATAFLOW REORDER —
// both QK chains issue back-to-back (shared kf4), K-prefetch moves up, then
// SM_e -> PV_e -> SM_o -> PV_o so softmax VALU overlaps PV MFMA drain.
__global__ __launch_bounds__(256, 2) void k_attn(
    const u16* __restrict__ Qf, const u16* __restrict__ Kf, const u16* __restrict__ Vf,
    u16* __restrict__ Co) {
  __shared__ float Xch[3][64][66];               // waves 1-3 partials
  __shared__ __align__(16) u16 OswE[32][64];
  __shared__ __align__(16) u16 OswO[32][64];
  const int bid = blockIdx.x;
  const int xcd = bid & 7, idx = bid >> 3;
  const int bh = (xcd << 2) | (idx & 3);
  const int p = idx >> 2;                        // 0..15
  const int b = bh >> 4, h = bh & 15;
  const int w = threadIdx.x >> 6;                // wave 0..3
  const int l = threadIdx.x & 63;
  const int lq = l & 31, hi = l >> 5;
  const float NEG = -3.0e38f;

  const u16* Kbase = Kf + ((size_t)(bh * 64) * 4) * 512 + l * 8;   // per 32-kv tau
  const u16* Vbase = Vf + ((size_t)(bh * 32) * 8) * 512 + l * 8;   // per 64-kv j

#pragma unroll 1
  for (int ph = 0; ph < 2; ++ph) {
    const int g = ph ? (31 - p) : p;
    const int n = g + 1;                         // 64-kv tiles needed
    const int js = (w * n) >> 2;
    const int je = ((w + 1) * n) >> 2;
    const bool dw = (w == 3);                    // diag owner
    const int t32s = 2 * js;
    const int t32e = dw ? 2 * (n - 1) : 2 * je;  // 32-kv loop end (diag excluded)
    const int tlim = dw ? t32e + 1 : t32e;       // prefetch validity bound

    const u16* Qe = Qf + (((size_t)(bh * 64 + 2 * g)) * 4) * 512 + l * 8;
    u16x8 qfe[4], qfo[4];
#pragma unroll
    for (int ss = 0; ss < 4; ++ss) {
      qfe[ss] = *(const u16x8*)(Qe + ss * 512);
      qfo[ss] = *(const u16x8*)(Qe + (4 + ss) * 512);
    }

    f32x16 o0e, o1e, o0o, o1o;
#pragma unroll
    for (int r = 0; r < 16; ++r) { o0e[r] = 0.f; o1e[r] = 0.f; o0o[r] = 0.f; o1o[r] = 0.f; }
    float lle = 0.f, llo = 0.f;

    u16x8 kf4[4], vf4[4];
    const bool havework = dw || (js < je);
    if (havework) {  // prologue: first 32-kv step's K and V
      const u16* pk = Kbase + ((size_t)t32s * 4) * 512;
      size_t vb = ((size_t)(t32s >> 1) * 8 + (size_t)(t32s & 1) * 2);
#pragma unroll
      for (int ss = 0; ss < 4; ++ss) kf4[ss] = *(const u16x8*)(pk + ss * 512);
      vf4[0] = *(const u16x8*)(Vbase + (vb + 0) * 512);
      vf4[1] = *(const u16x8*)(Vbase + (vb + 1) * 512);
      vf4[2] = *(const u16x8*)(Vbase + (vb + 4) * 512);
      vf4[3] = *(const u16x8*)(Vbase + (vb + 5) * 512);
    }

    for (int t32 = t32s; t32 < t32e; ++t32) {
      const bool pre = (t32 + 1 < tlim);
      u16x8 pfA, pfB, pcA, pcB;
      f32x16 se, so;
      // ---- both QK chains back-to-back (independent; both read kf4) ----
#pragma unroll
      for (int r = 0; r < 16; ++r) { se[r] = -16.f; so[r] = -16.f; }
      __builtin_amdgcn_s_setprio(1);
      se = mfma32(kf4[0], qfe[0], se);
      se = mfma32(kf4[1], qfe[1], se);
      se = mfma32(kf4[2], qfe[2], se);
      se = mfma32(kf4[3], qfe[3], se);
      so = mfma32(kf4[0], qfo[0], so);
      so = mfma32(kf4[1], qfo[1], so);
      so = mfma32(kf4[2], qfo[2], so);
      so = mfma32(kf4[3], qfo[3], so);
      __builtin_amdgcn_s_setprio(0);
      if (pre) {  // kf4 dead -> in-place K prefetch (early, more latency cover)
        const u16* pk = Kbase + ((size_t)(t32 + 1) * 4) * 512;
#pragma unroll
        for (int ss = 0; ss < 4; ++ss) kf4[ss] = *(const u16x8*)(pk + ss * 512);
      }
      // ---- softmax even (VALU) ----
#pragma unroll
      for (int r = 0; r < 16; ++r) se[r] = ex2(se[r]);
      lle += tsum16(se);
      pack2(se, pfA, pfB);
      // ---- PV even (MFMA) ----
      __builtin_amdgcn_s_setprio(1);
      o0e = mfma32(vf4[0], pfA, o0e);
      o0e = mfma32(vf4[1], pfB, o0e);
      o1e = mfma32(vf4[2], pfA, o1e);
      o1e = mfma32(vf4[3], pfB, o1e);
      __builtin_amdgcn_s_setprio(0);
      // ---- softmax odd (VALU; overlaps PV-even drain) ----
#pragma unroll
      for (int r = 0; r < 16; ++r) so[r] = ex2(so[r]);
      llo += tsum16(so);
      pack2(so, pcA, pcB);
      // ---- PV odd (MFMA) ----
      __builtin_amdgcn_s_setprio(1);
      o0o = mfma32(vf4[0], pcA, o0o);
      o0o = mfma32(vf4[1], pcB, o0o);
      o1o = mfma32(vf4[2], pcA, o1o);
      o1o = mfma32(vf4[3], pcB, o1o);
      __builtin_amdgcn_s_setprio(0);
      if (pre) {  // vf4 dead -> in-place V prefetch
        size_t vb = ((size_t)((t32 + 1) >> 1) * 8 + (size_t)((t32 + 1) & 1) * 2);
        vf4[0] = *(const u16x8*)(Vbase + (vb + 0) * 512);
        vf4[1] = *(const u16x8*)(Vbase + (vb + 1) * 512);
        vf4[2] = *(const u16x8*)(Vbase + (vb + 4) * 512);
        vf4[3] = *(const u16x8*)(Vbase + (vb + 5) * 512);
      }
    }

    if (dw) {  // peeled diagonal 64-kv tile: d0 = low 32 kv, d1 = high 32 kv
      // load d1's K/V into a second small buffer NOW (hides under d0 compute)
      u16x8 kf2[4], vf2[4];
      {
        const int t1 = 2 * n - 1;
        const u16* pk = Kbase + ((size_t)t1 * 4) * 512;
        size_t vb = ((size_t)(t1 >> 1) * 8 + (size_t)(t1 & 1) * 2);
#pragma unroll
        for (int ss = 0; ss < 4; ++ss) kf2[ss] = *(const u16x8*)(pk + ss * 512);
        vf2[0] = *(const u16x8*)(Vbase + (vb + 0) * 512);
        vf2[1] = *(const u16x8*)(Vbase + (vb + 1) * 512);
        vf2[2] = *(const u16x8*)(Vbase + (vb + 4) * 512);
        vf2[3] = *(const u16x8*)(Vbase + (vb + 5) * 512);
      }
      u16x8 pfA, pfB;
      f32x16 s;
      // d0, even tile: triangular mask (crow > lq)
#pragma unroll
      for (int r = 0; r < 16; ++r) s[r] = -16.f;
      s = mfma32(kf4[0], qfe[0], s);
      s = mfma32(kf4[1], qfe[1], s);
      s = mfma32(kf4[2], qfe[2], s);
      s = mfma32(kf4[3], qfe[3], s);
#pragma unroll
      for (int r = 0; r < 16; ++r) {
        int crow = (r & 3) + 8 * (r >> 2) + 4 * hi;
        if (crow > lq) s[r] = NEG;
      }
#pragma unroll
      for (int r = 0; r < 16; ++r) s[r] = ex2(s[r]);
      lle += tsum16(s);
      pack2(s, pfA, pfB);
      o0e = mfma32(vf4[0], pfA, o0e);
      o0e = mfma32(vf4[1], pfB, o0e);
      o1e = mfma32(vf4[2], pfA, o1e);
      o1e = mfma32(vf4[3], pfB, o1e);
      // d0, odd tile: fully visible
#pragma unroll
      for (int r = 0; r < 16; ++r) s[r] = -16.f;
      s = mfma32(kf4[0], qfo[0], s);
      s = mfma32(kf4[1], qfo[1], s);
      s = mfma32(kf4[2], qfo[2], s);
      s = mfma32(kf4[3], qfo[3], s);
#pragma unroll
      for (int r = 0; r < 16; ++r) s[r] = ex2(s[r]);
      llo += tsum16(s);
      pack2(s, pfA, pfB);
      o0o = mfma32(vf4[0], pfA, o0o);
      o0o = mfma32(vf4[1], pfB, o0o);
      o1o = mfma32(vf4[2], pfA, o1o);
      o1o = mfma32(vf4[3], pfB, o1o);
      // d1, odd tile only: triangular mask (crow > lq); even tile fully masked
#pragma unroll
      for (int r = 0; r < 16; ++r) s[r] = -16.f;
      s = mfma32(kf2[0], qfo[0], s);
      s = mfma32(kf2[1], qfo[1], s);
      s = mfma32(kf2[2], qfo[2], s);
      s = mfma32(kf2[3], qfo[3], s);
#pragma unroll
      for (int r = 0; r < 16; ++r) {
        int crow = (r & 3) + 8 * (r >> 2) + 4 * hi;
        if (crow > lq) s[r] = NEG;
      }
#pragma unroll
      for (int r = 0; r < 16; ++r) s[r] = ex2(s[r]);
      llo += tsum16(s);
      pack2(s, pfA, pfB);
      o0o = mfma32(vf2[0], pfA, o0o);
      o0o = mfma32(vf2[1], pfB, o0o);
      o1o = mfma32(vf2[2], pfA, o1o);
      o1o = mfma32(vf2[3], pfB, o1o);
    }

    // ---- single-round 3-slice merge (pure sums) ----
    if (w) {
      f32x2* xr = (f32x2*)(&Xch[w - 1][l][0]);
#pragma unroll
      for (int i = 0; i < 8; ++i) {
        xr[i]      = (f32x2){o0e[2 * i], o0e[2 * i + 1]};
        xr[8 + i]  = (f32x2){o1e[2 * i], o1e[2 * i + 1]};
        xr[16 + i] = (f32x2){o0o[2 * i], o0o[2 * i + 1]};
        xr[24 + i] = (f32x2){o1o[2 * i], o1o[2 * i + 1]};
      }
      xr[32] = (f32x2){lle, llo};
    }
    __syncthreads();
    if (w == 0) {
#pragma unroll
      for (int wv = 0; wv < 3; ++wv) {
        const f32x2* xr = (const f32x2*)(&Xch[wv][l][0]);
#pragma unroll
        for (int i = 0; i < 8; ++i) {
          f32x2 a = xr[i], bq = xr[8 + i], c = xr[16 + i], d = xr[24 + i];
          o0e[2 * i] += a[0]; o0e[2 * i + 1] += a[1];
          o1e[2 * i] += bq[0]; o1e[2 * i + 1] += bq[1];
          o0o[2 * i] += c[0]; o0o[2 * i + 1] += c[1];
          o1o[2 * i] += d[0]; o1o[2 * i + 1] += d[1];
        }
        f32x2 e = xr[32];
        lle += e[0]; llo += e[1];
      }
      lle += __shfl_xor(lle, 32);
      llo += __shfl_xor(llo, 32);
      {
        float inv = 1.0f / lle;
#pragma unroll
        for (int r = 0; r < 16; ++r) {
          int drow = (r & 3) + 8 * (r >> 2) + 4 * hi;
          *(u16*)swzb(OswE, lq, drow * 2) = f2bf(o0e[r] * inv);
          *(u16*)swzb(OswE, lq, (32 + drow) * 2) = f2bf(o1e[r] * inv);
        }
        u16* dst = Co + ((size_t)(b * S_ + 64 * g + lq)) * EMB_ + h * HS_ + hi * 32;
#pragma unroll
        for (int k = 0; k < 4; ++k) {
          u16x8 vv = *swzp(OswE, lq, (hi * 32 + k * 8) * 2);
          *(u16x8*)(dst + k * 8) = vv;
        }
      }
      {
        float inv = 1.0f / llo;
#pragma unroll
        for (int r = 0; r < 16; ++r) {
          int drow = (r & 3) + 8 * (r >> 2) + 4 * hi;
          *(u16*)swzb(OswO, lq, drow * 2) = f2bf(o0o[r] * inv);
          *(u16*)swzb(OswO, lq, (32 + drow) * 2) = f2bf(o1o[r] * inv);
        }
        u16* dst = Co + ((size_t)(b * S_ + 64 * g + 32 + lq)) * EMB_ + h * HS_ + hi * 32;
#pragma unroll
        for (int k = 0; k < 4; ++k) {
          u16x8 vv = *swzp(OswO, lq, (hi * 32 + k * 8) * 2);
          *(u16x8*)(dst + k * 8) = vv;
        }
      }
    }
    __syncthreads();   // protect Xch/Osw before next phase
  }
}

// ---------------- K3: out = concat @ Wo + bo (fp32 out), 64x128 tiles --------------
// Staging via global_load_lds (width 16). LDS dest LINEAR; global source PRE-SWIZZLED
// (chunk' = (l&7)^(l>>3), same 128B line); fragment reads keep the XOR swizzle.
__global__ __launch_bounds__(256) void k_outproj(
    const u16* __restrict__ Cc, const u16* __restrict__ Wot,
    const float* __restrict__ bo, float* __restrict__ out) {
  __shared__ __align__(16) u16 As[64][64];
  __shared__ __align__(16) u16 Bs[128][64];
  const int bid = blockIdx.x;
  const int xcd = bid & 7, sl = bid >> 3;
  const int mb = (xcd << 3) | (sl >> 3);
  const int nb = sl & 7;
  const int t = threadIdx.x;
  const int lane = t & 63, wv = t >> 6;
  const int lq = lane & 15, lg = lane >> 4;
  const int wr = wv >> 1, wc = wv & 1;
  const int lrow = lane >> 3;                       // row within 8-row group
  const int lchk = ((lane & 7) ^ (lane >> 3)) * 8;  // pre-swizzled u16 col offset
  f32x4 acc[2][4];
#pragma unroll
  for (int mi = 0; mi < 2; ++mi)
#pragma unroll
    for (int ni = 0; ni < 4; ++ni) { f32x4 z = {0.f, 0.f, 0.f, 0.f}; acc[mi][ni] = z; }
  const u16* ga0 = Cc + (size_t)(mb * 64 + wv * 16 + lrow) * EMB_ + lchk;
  const u16* ga1 = Cc + (size_t)(mb * 64 + wv * 16 + 8 + lrow) * EMB_ + lchk;
  const u16* gb0 = Wot + (size_t)(nb * 128 + wv * 32 + lrow) * EMB_ + lchk;
  const u16* gb1 = Wot + (size_t)(nb * 128 + wv * 32 + 8 + lrow) * EMB_ + lchk;
  const u16* gb2 = Wot + (size_t)(nb * 128 + wv * 32 + 16 + lrow) * EMB_ + lchk;
  const u16* gb3 = Wot + (size_t)(nb * 128 + wv * 32 + 24 + lrow) * EMB_ + lchk;
  typedef __attribute__((address_space(3))) void lds_v;
  typedef const __attribute__((address_space(1))) void glb_v;
  for (int kt = 0; kt < 16; ++kt) {
    __syncthreads();   // previous tile's reads done
    const int co = kt * 64;
    __builtin_amdgcn_global_load_lds((glb_v*)(ga0 + co), (lds_v*)&As[wv * 16][0], 16, 0, 0);
    __builtin_amdgcn_global_load_lds((glb_v*)(ga1 + co), (lds_v*)&As[wv * 16 + 8][0], 16, 0, 0);
    __builtin_amdgcn_global_load_lds((glb_v*)(gb0 + co), (lds_v*)&Bs[wv * 32][0], 16, 0, 0);
    __builtin_amdgcn_global_load_lds((glb_v*)(gb1 + co), (lds_v*)&Bs[wv * 32 + 8][0], 16, 0, 0);
    __builtin_amdgcn_global_load_lds((glb_v*)(gb2 + co), (lds_v*)&Bs[wv * 32 + 16][0], 16, 0, 0);
    __builtin_amdgcn_global_load_lds((glb_v*)(gb3 + co), (lds_v*)&Bs[wv * 32 + 24][0], 16, 0, 0);
    __syncthreads();   // drains vmcnt (compiler emits waitcnt before barrier)
#pragma unroll
    for (int kf = 0; kf < 2; ++kf) {
      u16x8 af[2], bf[4];
#pragma unroll
      for (int mi = 0; mi < 2; ++mi)
        af[mi] = *swzp(As, wr * 32 + mi * 16 + lq, kf * 64 + lg * 16);
#pragma unroll
      for (int ni = 0; ni < 4; ++ni)
        bf[ni] = *swzp(Bs, wc * 64 + ni * 16 + lq, kf * 64 + lg * 16);
#pragma unroll
      for (int mi = 0; mi < 2; ++mi)
#pragma unroll
        for (int ni = 0; ni < 4; ++ni)
          acc[mi][ni] = mfma16(af[mi], bf[ni], acc[mi][ni]);
    }
  }
#pragma unroll
  for (int mi = 0; mi < 2; ++mi) {
#pragma unroll
    for (int ni = 0; ni < 4; ++ni) {
      int col = nb * 128 + wc * 64 + ni * 16 + lq;
      float bv = bo[col];
#pragma unroll
      for (int rr = 0; rr < 4; ++rr) {
        int row = mb * 64 + wr * 32 + mi * 16 + lg * 4 + rr;
        out[(size_t)row * EMB_ + col] = acc[mi][ni][rr] + bv;
      }
    }
  }
}

extern "C" void kernel_launch(void* const* d_in, const int* in_sizes, int n_in,
                              void* d_out, int out_size, void* d_ws, size_t ws_size,
                              hipStream_t stream) {
  const float* xk = (const float*)d_in[0];
  const float* xv = (const float*)d_in[1];
  const float* xq = (const float*)d_in[2];
  const float* Wk = (const float*)d_in[3];
  const float* Wv = (const float*)d_in[4];
  const float* Wq = (const float*)d_in[5];
  const float* Wo = (const float*)d_in[6];
  const float* bo = (const float*)d_in[7];
  float* out = (float*)d_out;
  char* ws = (char*)d_ws;
  const size_t MB8 = (size_t)8 * 1024 * 1024;
  u16* Qfw = (u16*)(ws);             // fragment-major Q (pre-scaled, exp2 domain)
  u16* Kfw = (u16*)(ws + MB8);       // fragment-major K
  u16* Vfw = (u16*)(ws + 2 * MB8);   // fragment-major V^T
  u16* Cw  = (u16*)(ws + 3 * MB8);   // concat [2][2048][1024]
  u16* Wot = (u16*)(ws + 4 * MB8);   // [1024][1024]

  k_transpose_wo<<<dim3(16, 16), 256, 0, stream>>>(Wo, Wot);
  k_proj<<<dim3(32, 32, 3), 256, 0, stream>>>(xq, xk, xv, Wq, Wk, Wv, Qfw, Kfw, Vfw);
  k_attn<<<512, 256, 0, stream>>>(Qfw, Kfw, Vfw, Cw);
  k_outproj<<<512, 256, 0, stream>>>(Cw, Wot, bo, out);
}

// Round 15
// 62.530 us; speedup vs baseline: 1.1144x; 1.0299x over previous
//
#include <hip/hip_runtime.h>
#include <hip/hip_bf16.h>
#include <cstdint>

typedef unsigned short u16;
typedef __bf16 bf16x8 __attribute__((ext_vector_type(8)));
typedef u16 u16x8 __attribute__((ext_vector_type(8)));
typedef unsigned u32x4 __attribute__((ext_vector_type(4)));
typedef float f32x2 __attribute__((ext_vector_type(2)));
typedef float f32x4 __attribute__((ext_vector_type(4)));
typedef float f32x16 __attribute__((ext_vector_type(16)));

#define B_ 2
#define S_ 2048
#define H_ 16
#define HS_ 64
#define EMB_ 1024
#define QSCALE 0.022097086912079608f  /* 1/sqrt(2048) */
#define LOG2E  1.4426950408889634f    /* folded into Q so softmax uses exp2 */

static __device__ __forceinline__ u16 f2bf(float f) {
  unsigned int u = __float_as_uint(f);
  u += 0x7fffu + ((u >> 16) & 1u);   // RNE
  return (u16)(u >> 16);
}

// single-instruction 2^x
static __device__ __forceinline__ float ex2(float x) {
#if __has_builtin(__builtin_amdgcn_exp2f)
  return __builtin_amdgcn_exp2f(x);
#else
  float r; asm("v_exp_f32 %0, %1" : "=v"(r) : "v"(x)); return r;
#endif
}

// depth-4 tree sum of 16 floats
static __device__ __forceinline__ float tsum16(const f32x16& s) {
  float a0 = s[0] + s[1],  a1 = s[2] + s[3];
  float a2 = s[4] + s[5],  a3 = s[6] + s[7];
  float a4 = s[8] + s[9],  a5 = s[10] + s[11];
  float a6 = s[12] + s[13], a7 = s[14] + s[15];
  a0 += a1; a2 += a3; a4 += a5; a6 += a7;
  a0 += a2; a4 += a6;
  return a0 + a4;
}

static __device__ __forceinline__ f32x4 mfma16(u16x8 a, u16x8 b, f32x4 c) {
  return __builtin_amdgcn_mfma_f32_16x16x32_bf16(
      __builtin_bit_cast(bf16x8, a), __builtin_bit_cast(bf16x8, b), c, 0, 0, 0);
}
static __device__ __forceinline__ f32x16 mfma32(u16x8 a, u16x8 b, f32x16 c) {
  return __builtin_amdgcn_mfma_f32_32x32x16_bf16(
      __builtin_bit_cast(bf16x8, a), __builtin_bit_cast(bf16x8, b), c, 0, 0, 0);
}

// XOR-swizzled address into a tile with 128B row stride (LDS bank-conflict fix).
static __device__ __forceinline__ char* swzb(void* base, int row, int colbyte) {
  return (char*)base + ((row * 128 + colbyte) ^ ((row & 7) << 4));
}
static __device__ __forceinline__ u16x8* swzp(void* base, int row, int colbyte) {
  return (u16x8*)swzb(base, row, colbyte);
}

// cvt_pk two f32 pairs to packed bf16 words, then permlane32_swap (T12).
static __device__ __forceinline__ void pk_swap(float a0, float a1, float b0, float b1,
                                               unsigned& x, unsigned& y) {
  unsigned A, Bv;
  asm("v_cvt_pk_bf16_f32 %0, %1, %2" : "=v"(A) : "v"(a0), "v"(a1));
  asm("v_cvt_pk_bf16_f32 %0, %1, %2" : "=v"(Bv) : "v"(b0), "v"(b1));
  asm("v_permlane32_swap_b32 %0, %1" : "+v"(A), "+v"(Bv));
  x = A; y = Bv;
}

// P (16 f32 = one 32-kv half-tile for one q-tile) -> two PV B-fragments
static __device__ __forceinline__ void pack2(const f32x16& s0, u16x8& pf0, u16x8& pf1) {
  unsigned w0, w1, w2, w3;
  pk_swap(s0[0], s0[1], s0[4], s0[5], w0, w2);
  pk_swap(s0[2], s0[3], s0[6], s0[7], w1, w3);
  pf0 = __builtin_bit_cast(u16x8, (u32x4){w0, w1, w2, w3});
  pk_swap(s0[8], s0[9], s0[12], s0[13], w0, w2);
  pk_swap(s0[10], s0[11], s0[14], s0[15], w1, w3);
  pf1 = __builtin_bit_cast(u16x8, (u32x4){w0, w1, w2, w3});
}

// ---------------- K0: Wo[k][n] fp32 -> Wot[n][k] bf16 ----------------
__global__ __launch_bounds__(256) void k_transpose_wo(const float* __restrict__ Wo,
                                                      u16* __restrict__ Wot) {
  __shared__ __align__(16) u16 T[64][72];
  const int kb = blockIdx.y * 64, nb = blockIdx.x * 64;
  const int r = threadIdx.x >> 2;
  const int c0 = (threadIdx.x & 3) << 4;
  const float* src = Wo + (size_t)(kb + r) * EMB_ + nb + c0;
#pragma unroll
  for (int i = 0; i < 16; i += 4) {
    float4 f = *(const float4*)(src + i);
    T[c0 + i + 0][r] = f2bf(f.x);
    T[c0 + i + 1][r] = f2bf(f.y);
    T[c0 + i + 2][r] = f2bf(f.z);
    T[c0 + i + 3][r] = f2bf(f.w);
  }
  __syncthreads();
  u16* dst = Wot + (size_t)(nb + r) * EMB_ + kb + c0;
  *(u16x8*)(dst)     = *(const u16x8*)&T[r][c0];
  *(u16x8*)(dst + 8) = *(const u16x8*)&T[r][c0 + 8];
}

// ---------------- K1: projections -> FRAGMENT-MAJOR layouts (tn = blockIdx.z) ----
// Qf: [bh][t:64][slice:4][lane:64][8]   = Q[t*32+(l&31)][slice*16+(l>>5)*8+j] * QSCALE*LOG2E
// Kf: [bh][tau:64][slice:4][lane:64][8] = K[tau*32+(l&31)][slice*16+(l>>5)*8+j]
// Vf: [bh][j:32][eta:2][kap:4][lane:64][8] = Vt[eta*32+(l&31)][j*64+kap*16+(l>>5)*8+jj]
__global__ __launch_bounds__(256) void k_proj(
    const float* __restrict__ xq, const float* __restrict__ xk, const float* __restrict__ xv,
    const float* __restrict__ Wq, const float* __restrict__ Wk, const float* __restrict__ Wv,
    u16* __restrict__ Qf, u16* __restrict__ Kf, u16* __restrict__ Vf) {
  __shared__ __align__(16) u16 Xb[64][64];
  __shared__ __align__(16) u16 Wb[64][64];   // Wb[e][d] = W[d][e]
  __shared__ __align__(16) u16 Tt[64][64];
  const int sb = blockIdx.x;   // s-block 0..31
  const int bh = blockIdx.y;   // 0..31
  const int tn = blockIdx.z;   // 0=Q, 1=K, 2=V
  const int b = bh >> 4, h = bh & 15;
  const int t = threadIdx.x;
  const int r = t >> 2, c0 = (t & 3) << 4;
  const int lane = t & 63, wv = t >> 6;
  const int lq = lane & 15, lg = lane >> 4;
  const int l31 = lane & 31, hi = lane >> 5;
  const float* xs = (tn == 0) ? xq : (tn == 1) ? xk : xv;
  const float* wsp3 = (tn == 0) ? Wq : (tn == 1) ? Wk : Wv;

  const float* src = xs + ((size_t)(b * S_ + sb * 64 + r)) * HS_ + c0;
#pragma unroll
  for (int i = 0; i < 16; i += 8) {
    float4 fa = *(const float4*)(src + i);
    float4 fb = *(const float4*)(src + i + 4);
    u16x8 v = {f2bf(fa.x), f2bf(fa.y), f2bf(fa.z), f2bf(fa.w),
               f2bf(fb.x), f2bf(fb.y), f2bf(fb.z), f2bf(fb.w)};
    *swzp(Xb, r, (c0 + i) * 2) = v;
  }
  const float* wsp = wsp3 + ((size_t)(h * HS_ + r)) * HS_ + c0;
#pragma unroll
  for (int i = 0; i < 16; i += 4) {
    float4 f = *(const float4*)(wsp + i);
    *(u16*)swzb(Wb, c0 + i + 0, r * 2) = f2bf(f.x);
    *(u16*)swzb(Wb, c0 + i + 1, r * 2) = f2bf(f.y);
    *(u16*)swzb(Wb, c0 + i + 2, r * 2) = f2bf(f.z);
    *(u16*)swzb(Wb, c0 + i + 3, r * 2) = f2bf(f.w);
  }
  __syncthreads();
  if (tn < 2) {
    u16x8 a0 = *swzp(Xb, wv * 16 + lq, lg * 16);
    u16x8 a1 = *swzp(Xb, wv * 16 + lq, 64 + lg * 16);
    const float osc = (tn == 0) ? (QSCALE * LOG2E) : 1.0f;
#pragma unroll
    for (int et = 0; et < 4; ++et) {
      u16x8 b0 = *swzp(Wb, et * 16 + lq, lg * 16);
      u16x8 b1 = *swzp(Wb, et * 16 + lq, 64 + lg * 16);
      f32x4 acc = {0.f, 0.f, 0.f, 0.f};
      acc = mfma16(a0, b0, acc);
      acc = mfma16(a1, b1, acc);
#pragma unroll
      for (int rr = 0; rr < 4; ++rr)
        *(u16*)swzb(Tt, wv * 16 + lg * 4 + rr, (et * 16 + lq) * 2) = f2bf(acc[rr] * osc);
    }
  } else {
    u16x8 xb0 = *swzp(Xb, wv * 16 + lq, lg * 16);
    u16x8 xb1 = *swzp(Xb, wv * 16 + lq, 64 + lg * 16);
#pragma unroll
    for (int et = 0; et < 4; ++et) {
      u16x8 a0 = *swzp(Wb, et * 16 + lq, lg * 16);
      u16x8 a1 = *swzp(Wb, et * 16 + lq, 64 + lg * 16);
      f32x4 acc = {0.f, 0.f, 0.f, 0.f};
      acc = mfma16(a0, xb0, acc);
      acc = mfma16(a1, xb1, acc);
#pragma unroll
      for (int rr = 0; rr < 4; ++rr)
        *(u16*)swzb(Tt, et * 16 + lg * 4 + rr, (wv * 16 + lq) * 2) = f2bf(acc[rr]);
    }
  }
  __syncthreads();
  if (tn < 2) {
    u16* dst = (tn == 0) ? Qf : Kf;
#pragma unroll
    for (int tl = 0; tl < 2; ++tl) {
      u16x8 v = *swzp(Tt, tl * 32 + l31, wv * 32 + hi * 16);
      size_t off = (((size_t)(bh * 64 + sb * 2 + tl)) * 4 + wv) * 512 + lane * 8;
      *(u16x8*)(dst + off) = v;
    }
  } else {
#pragma unroll
    for (int eta = 0; eta < 2; ++eta) {
      u16x8 v = *swzp(Tt, eta * 32 + l31, wv * 32 + hi * 16);
      size_t off = ((((size_t)(bh * 32 + sb)) * 2 + eta) * 4 + wv) * 512 + lane * 8;
      *(u16x8*)(Vf + off) = v;
    }
  }
}

// ---------------- K2: causal flash attention, 64 q-rows/wave, 32-kv steps ----------
// R12 known-good inner order (single score buffer; QK_e,SM_e,PV_e,QK_o,K-pre,SM_o,
// PV_o,V-pre). R15 deltas (structural only, NO forced wave bound): diag reuses
// kf4/vf4 (-32 VGPR) and Xch[2] two-round merge (LDS 41KB) so 3 blocks/CU engage
// IF the natural VGPR allocation lands <=170. launch_bounds stays (256,2).
__global__ __launch_bounds__(256, 2) void k_attn(
    const u16* __restrict__ Qf, const u16* __restrict__ Kf, const u16* __restrict__ Vf,
    u16* __restrict__ Co) {
  __shared__ float Xch[2][64][66];               // merge slices (two-round tree)
  __shared__ __align__(16) u16 OswE[32][64];
  __shared__ __align__(16) u16 OswO[32][64];
  const int bid = blockIdx.x;
  const int xcd = bid & 7, idx = bid >> 3;
  const int bh = (xcd << 2) | (idx & 3);
  const int p = idx >> 2;                        // 0..15
  const int b = bh >> 4, h = bh & 15;
  const int w = threadIdx.x >> 6;                // wave 0..3
  const int l = threadIdx.x & 63;
  const int lq = l & 31, hi = l >> 5;
  const float NEG = -3.0e38f;

  const u16* Kbase = Kf + ((size_t)(bh * 64) * 4) * 512 + l * 8;   // per 32-kv tau
  const u16* Vbase = Vf + ((size_t)(bh * 32) * 8) * 512 + l * 8;   // per 64-kv j

#pragma unroll 1
  for (int ph = 0; ph < 2; ++ph) {
    const int g = ph ? (31 - p) : p;
    const int n = g + 1;                         // 64-kv tiles needed
    const int js = (w * n) >> 2;
    const int je = ((w + 1) * n) >> 2;
    const bool dw = (w == 3);                    // diag owner
    const int t32s = 2 * js;
    const int t32e = dw ? 2 * (n - 1) : 2 * je;  // 32-kv loop end (diag excluded)
    const int tlim = dw ? t32e + 1 : t32e;       // prefetch validity bound

    const u16* Qe = Qf + (((size_t)(bh * 64 + 2 * g)) * 4) * 512 + l * 8;
    u16x8 qfe[4], qfo[4];
#pragma unroll
    for (int ss = 0; ss < 4; ++ss) {
      qfe[ss] = *(const u16x8*)(Qe + ss * 512);
      qfo[ss] = *(const u16x8*)(Qe + (4 + ss) * 512);
    }

    f32x16 o0e, o1e, o0o, o1o;
#pragma unroll
    for (int r = 0; r < 16; ++r) { o0e[r] = 0.f; o1e[r] = 0.f; o0o[r] = 0.f; o1o[r] = 0.f; }
    float lle = 0.f, llo = 0.f;

    u16x8 kf4[4], vf4[4];
    const bool havework = dw || (js < je);
    if (havework) {  // prologue: first 32-kv step's K and V (dw: d0 if loop empty)
      const u16* pk = Kbase + ((size_t)t32s * 4) * 512;
      size_t vb = ((size_t)(t32s >> 1) * 8 + (size_t)(t32s & 1) * 2);
#pragma unroll
      for (int ss = 0; ss < 4; ++ss) kf4[ss] = *(const u16x8*)(pk + ss * 512);
      vf4[0] = *(const u16x8*)(Vbase + (vb + 0) * 512);
      vf4[1] = *(const u16x8*)(Vbase + (vb + 1) * 512);
      vf4[2] = *(const u16x8*)(Vbase + (vb + 4) * 512);
      vf4[3] = *(const u16x8*)(Vbase + (vb + 5) * 512);
    }

    for (int t32 = t32s; t32 < t32e; ++t32) {
      const bool pre = (t32 + 1 < tlim);
      u16x8 pfA, pfB;
      f32x16 s;
      // ---- even q-tile ----
#pragma unroll
      for (int r = 0; r < 16; ++r) s[r] = -16.f;
      __builtin_amdgcn_s_setprio(1);
      s = mfma32(kf4[0], qfe[0], s);
      s = mfma32(kf4[1], qfe[1], s);
      s = mfma32(kf4[2], qfe[2], s);
      s = mfma32(kf4[3], qfe[3], s);
      __builtin_amdgcn_s_setprio(0);
#pragma unroll
      for (int r = 0; r < 16; ++r) s[r] = ex2(s[r]);
      lle += tsum16(s);
      pack2(s, pfA, pfB);
      __builtin_amdgcn_s_setprio(1);
      o0e = mfma32(vf4[0], pfA, o0e);
      o0e = mfma32(vf4[1], pfB, o0e);
      o1e = mfma32(vf4[2], pfA, o1e);
      o1e = mfma32(vf4[3], pfB, o1e);
      __builtin_amdgcn_s_setprio(0);
      // ---- odd q-tile (K dies after these issue) ----
#pragma unroll
      for (int r = 0; r < 16; ++r) s[r] = -16.f;
      __builtin_amdgcn_s_setprio(1);
      s = mfma32(kf4[0], qfo[0], s);
      s = mfma32(kf4[1], qfo[1], s);
      s = mfma32(kf4[2], qfo[2], s);
      s = mfma32(kf4[3], qfo[3], s);
      __builtin_amdgcn_s_setprio(0);
      if (pre) {  // in-place K prefetch
        const u16* pk = Kbase + ((size_t)(t32 + 1) * 4) * 512;
#pragma unroll
        for (int ss = 0; ss < 4; ++ss) kf4[ss] = *(const u16x8*)(pk + ss * 512);
      }
#pragma unroll
      for (int r = 0; r < 16; ++r) s[r] = ex2(s[r]);
      llo += tsum16(s);
      pack2(s, pfA, pfB);
      __builtin_amdgcn_s_setprio(1);
      o0o = mfma32(vf4[0], pfA, o0o);
      o0o = mfma32(vf4[1], pfB, o0o);
      o1o = mfma32(vf4[2], pfA, o1o);
      o1o = mfma32(vf4[3], pfB, o1o);
      __builtin_amdgcn_s_setprio(0);
      if (pre) {  // in-place V prefetch
        size_t vb = ((size_t)((t32 + 1) >> 1) * 8 + (size_t)((t32 + 1) & 1) * 2);
        vf4[0] = *(const u16x8*)(Vbase + (vb + 0) * 512);
        vf4[1] = *(const u16x8*)(Vbase + (vb + 1) * 512);
        vf4[2] = *(const u16x8*)(Vbase + (vb + 4) * 512);
        vf4[3] = *(const u16x8*)(Vbase + (vb + 5) * 512);
      }
    }

    if (dw) {  // peeled diag tile (kf4/vf4 hold d0): d0-even, d0-odd, then d1-odd
      u16x8 pfA, pfB;
      f32x16 s;
      // d0, even tile: triangular mask (crow > lq)
#pragma unroll
      for (int r = 0; r < 16; ++r) s[r] = -16.f;
      s = mfma32(kf4[0], qfe[0], s);
      s = mfma32(kf4[1], qfe[1], s);
      s = mfma32(kf4[2], qfe[2], s);
      s = mfma32(kf4[3], qfe[3], s);
#pragma unroll
      for (int r = 0; r < 16; ++r) {
        int crow = (r & 3) + 8 * (r >> 2) + 4 * hi;
        if (crow > lq) s[r] = NEG;
      }
#pragma unroll
      for (int r = 0; r < 16; ++r) s[r] = ex2(s[r]);
      lle += tsum16(s);
      pack2(s, pfA, pfB);
      o0e = mfma32(vf4[0], pfA, o0e);
      o0e = mfma32(vf4[1], pfB, o0e);
      o1e = mfma32(vf4[2], pfA, o1e);
      o1e = mfma32(vf4[3], pfB, o1e);
      // d0, odd tile: fully visible; after QK, kf4 dies -> reload with K[d1]
#pragma unroll
      for (int r = 0; r < 16; ++r) s[r] = -16.f;
      s = mfma32(kf4[0], qfo[0], s);
      s = mfma32(kf4[1], qfo[1], s);
      s = mfma32(kf4[2], qfo[2], s);
      s = mfma32(kf4[3], qfo[3], s);
      {
        const int t1 = 2 * n - 1;
        const u16* pk = Kbase + ((size_t)t1 * 4) * 512;
#pragma unroll
        for (int ss = 0; ss < 4; ++ss) kf4[ss] = *(const u16x8*)(pk + ss * 512);
      }
#pragma unroll
      for (int r = 0; r < 16; ++r) s[r] = ex2(s[r]);
      llo += tsum16(s);
      pack2(s, pfA, pfB);
      o0o = mfma32(vf4[0], pfA, o0o);
      o0o = mfma32(vf4[1], pfB, o0o);
      o1o = mfma32(vf4[2], pfA, o1o);
      o1o = mfma32(vf4[3], pfB, o1o);
      {  // vf4 dies after d0 PV -> reload with V[d1]
        const int t1 = 2 * n - 1;
        size_t vb = ((size_t)(t1 >> 1) * 8 + (size_t)(t1 & 1) * 2);
        vf4[0] = *(const u16x8*)(Vbase + (vb + 0) * 512);
        vf4[1] = *(const u16x8*)(Vbase + (vb + 1) * 512);
        vf4[2] = *(const u16x8*)(Vbase + (vb + 4) * 512);
        vf4[3] = *(const u16x8*)(Vbase + (vb + 5) * 512);
      }
      // d1, odd tile only (even fully masked): triangular mask
#pragma unroll
      for (int r = 0; r < 16; ++r) s[r] = -16.f;
      s = mfma32(kf4[0], qfo[0], s);
      s = mfma32(kf4[1], qfo[1], s);
      s = mfma32(kf4[2], qfo[2], s);
      s = mfma32(kf4[3], qfo[3], s);
#pragma unroll
      for (int r = 0; r < 16; ++r) {
        int crow = (r & 3) + 8 * (r >> 2) + 4 * hi;
        if (crow > lq) s[r] = NEG;
      }
#pragma unroll
      for (int r = 0; r < 16; ++r) s[r] = ex2(s[r]);
      llo += tsum16(s);
      pack2(s, pfA, pfB);
      o0o = mfma32(vf4[0], pfA, o0o);
      o0o = mfma32(vf4[1], pfB, o0o);
      o1o = mfma32(vf4[2], pfA, o1o);
      o1o = mfma32(vf4[3], pfB, o1o);
    }

    // ---- two-round tree merge (pure sums): (w0+=w1, w2+=w3) then w0+=w2 ----
    if (w == 1 || w == 3) {
      f32x2* xr = (f32x2*)(&Xch[w >> 1][l][0]);
#pragma unroll
      for (int i = 0; i < 8; ++i) {
        xr[i]      = (f32x2){o0e[2 * i], o0e[2 * i + 1]};
        xr[8 + i]  = (f32x2){o1e[2 * i], o1e[2 * i + 1]};
        xr[16 + i] = (f32x2){o0o[2 * i], o0o[2 * i + 1]};
        xr[24 + i] = (f32x2){o1o[2 * i], o1o[2 * i + 1]};
      }
      xr[32] = (f32x2){lle, llo};
    }
    __syncthreads();
    if (w == 0 || w == 2) {
      const f32x2* xr = (const f32x2*)(&Xch[w >> 1][l][0]);
#pragma unroll
      for (int i = 0; i < 8; ++i) {
        f32x2 a = xr[i], bq = xr[8 + i], c = xr[16 + i], d = xr[24 + i];
        o0e[2 * i] += a[0]; o0e[2 * i + 1] += a[1];
        o1e[2 * i] += bq[0]; o1e[2 * i + 1] += bq[1];
        o0o[2 * i] += c[0]; o0o[2 * i + 1] += c[1];
        o1o[2 * i] += d[0]; o1o[2 * i + 1] += d[1];
      }
      f32x2 e = xr[32];
      lle += e[0]; llo += e[1];
    }
    __syncthreads();
    if (w == 2) {
      f32x2* xr = (f32x2*)(&Xch[0][l][0]);
#pragma unroll
      for (int i = 0; i < 8; ++i) {
        xr[i]      = (f32x2){o0e[2 * i], o0e[2 * i + 1]};
        xr[8 + i]  = (f32x2){o1e[2 * i], o1e[2 * i + 1]};
        xr[16 + i] = (f32x2){o0o[2 * i], o0o[2 * i + 1]};
        xr[24 + i] = (f32x2){o1o[2 * i], o1o[2 * i + 1]};
      }
      xr[32] = (f32x2){lle, llo};
    }
    __syncthreads();
    if (w == 0) {
      {
        const f32x2* xr = (const f32x2*)(&Xch[0][l][0]);
#pragma unroll
        for (int i = 0; i < 8; ++i) {
          f32x2 a = xr[i], bq = xr[8 + i], c = xr[16 + i], d = xr[24 + i];
          o0e[2 * i] += a[0]; o0e[2 * i + 1] += a[1];
          o1e[2 * i] += bq[0]; o1e[2 * i + 1] += bq[1];
          o0o[2 * i] += c[0]; o0o[2 * i + 1] += c[1];
          o1o[2 * i] += d[0]; o1o[2 * i + 1] += d[1];
        }
        f32x2 e = xr[32];
        lle += e[0]; llo += e[1];
      }
      lle += __shfl_xor(lle, 32);
      llo += __shfl_xor(llo, 32);
      {
        float inv = 1.0f / lle;
#pragma unroll
        for (int r = 0; r < 16; ++r) {
          int drow = (r & 3) + 8 * (r >> 2) + 4 * hi;
          *(u16*)swzb(OswE, lq, drow * 2) = f2bf(o0e[r] * inv);
          *(u16*)swzb(OswE, lq, (32 + drow) * 2) = f2bf(o1e[r] * inv);
        }
        u16* dst = Co + ((size_t)(b * S_ + 64 * g + lq)) * EMB_ + h * HS_ + hi * 32;
#pragma unroll
        for (int k = 0; k < 4; ++k) {
          u16x8 vv = *swzp(OswE, lq, (hi * 32 + k * 8) * 2);
          *(u16x8*)(dst + k * 8) = vv;
        }
      }
      {
        float inv = 1.0f / llo;
#pragma unroll
        for (int r = 0; r < 16; ++r) {
          int drow = (r & 3) + 8 * (r >> 2) + 4 * hi;
          *(u16*)swzb(OswO, lq, drow * 2) = f2bf(o0o[r] * inv);
          *(u16*)swzb(OswO, lq, (32 + drow) * 2) = f2bf(o1o[r] * inv);
        }
        u16* dst = Co + ((size_t)(b * S_ + 64 * g + 32 + lq)) * EMB_ + h * HS_ + hi * 32;
#pragma unroll
        for (int k = 0; k < 4; ++k) {
          u16x8 vv = *swzp(OswO, lq, (hi * 32 + k * 8) * 2);
          *(u16x8*)(dst + k * 8) = vv;
        }
      }
    }
    __syncthreads();   // protect Xch/Osw before next phase
  }
}

// ---------------- K3: out = concat @ Wo + bo (fp32 out), 64x128 tiles --------------
// Staging via global_load_lds (width 16). LDS dest LINEAR; global source PRE-SWIZZLED
// (chunk' = (l&7)^(l>>3), same 128B line); fragment reads keep the XOR swizzle.
__global__ __launch_bounds__(256) void k_outproj(
    const u16* __restrict__ Cc, const u16* __restrict__ Wot,
    const float* __restrict__ bo, float* __restrict__ out) {
  __shared__ __align__(16) u16 As[64][64];
  __shared__ __align__(16) u16 Bs[128][64];
  const int bid = blockIdx.x;
  const int xcd = bid & 7, sl = bid >> 3;
  const int mb = (xcd << 3) | (sl >> 3);
  const int nb = sl & 7;
  const int t = threadIdx.x;
  const int lane = t & 63, wv = t >> 6;
  const int lq = lane & 15, lg = lane >> 4;
  const int wr = wv >> 1, wc = wv & 1;
  const int lrow = lane >> 3;                       // row within 8-row group
  const int lchk = ((lane & 7) ^ (lane >> 3)) * 8;  // pre-swizzled u16 col offset
  f32x4 acc[2][4];
#pragma unroll
  for (int mi = 0; mi < 2; ++mi)
#pragma unroll
    for (int ni = 0; ni < 4; ++ni) { f32x4 z = {0.f, 0.f, 0.f, 0.f}; acc[mi][ni] = z; }
  const u16* ga0 = Cc + (size_t)(mb * 64 + wv * 16 + lrow) * EMB_ + lchk;
  const u16* ga1 = Cc + (size_t)(mb * 64 + wv * 16 + 8 + lrow) * EMB_ + lchk;
  const u16* gb0 = Wot + (size_t)(nb * 128 + wv * 32 + lrow) * EMB_ + lchk;
  const u16* gb1 = Wot + (size_t)(nb * 128 + wv * 32 + 8 + lrow) * EMB_ + lchk;
  const u16* gb2 = Wot + (size_t)(nb * 128 + wv * 32 + 16 + lrow) * EMB_ + lchk;
  const u16* gb3 = Wot + (size_t)(nb * 128 + wv * 32 + 24 + lrow) * EMB_ + lchk;
  typedef __attribute__((address_space(3))) void lds_v;
  typedef const __attribute__((address_space(1))) void glb_v;
  for (int kt = 0; kt < 16; ++kt) {
    __syncthreads();   // previous tile's reads done
    const int co = kt * 64;
    __builtin_amdgcn_global_load_lds((glb_v*)(ga0 + co), (lds_v*)&As[wv * 16][0], 16, 0, 0);
    __builtin_amdgcn_global_load_lds((glb_v*)(ga1 + co), (lds_v*)&As[wv * 16 + 8][0], 16, 0, 0);
    __builtin_amdgcn_global_load_lds((glb_v*)(gb0 + co), (lds_v*)&Bs[wv * 32][0], 16, 0, 0);
    __builtin_amdgcn_global_load_lds((glb_v*)(gb1 + co), (lds_v*)&Bs[wv * 32 + 8][0], 16, 0, 0);
    __builtin_amdgcn_global_load_lds((glb_v*)(gb2 + co), (lds_v*)&Bs[wv * 32 + 16][0], 16, 0, 0);
    __builtin_amdgcn_global_load_lds((glb_v*)(gb3 + co), (lds_v*)&Bs[wv * 32 + 24][0], 16, 0, 0);
    __syncthreads();   // drains vmcnt (compiler emits waitcnt before barrier)
#pragma unroll
    for (int kf = 0; kf < 2; ++kf) {
      u16x8 af[2], bf[4];
#pragma unroll
      for (int mi = 0; mi < 2; ++mi)
        af[mi] = *swzp(As, wr * 32 + mi * 16 + lq, kf * 64 + lg * 16);
#pragma unroll
      for (int ni = 0; ni < 4; ++ni)
        bf[ni] = *swzp(Bs, wc * 64 + ni * 16 + lq, kf * 64 + lg * 16);
#pragma unroll
      for (int mi = 0; mi < 2; ++mi)
#pragma unroll
        for (int ni = 0; ni < 4; ++ni)
          acc[mi][ni] = mfma16(af[mi], bf[ni], acc[mi][ni]);
    }
  }
#pragma unroll
  for (int mi = 0; mi < 2; ++mi) {
#pragma unroll
    for (int ni = 0; ni < 4; ++ni) {
      int col = nb * 128 + wc * 64 + ni * 16 + lq;
      float bv = bo[col];
#pragma unroll
      for (int rr = 0; rr < 4; ++rr) {
        int row = mb * 64 + wr * 32 + mi * 16 + lg * 4 + rr;
        out[(size_t)row * EMB_ + col] = acc[mi][ni][rr] + bv;
      }
    }
  }
}

extern "C" void kernel_launch(void* const* d_in, const int* in_sizes, int n_in,
                              void* d_out, int out_size, void* d_ws, size_t ws_size,
                              hipStream_t stream) {
  const float* xk = (const float*)d_in[0];
  const float* xv = (const float*)d_in[1];
  const float* xq = (const float*)d_in[2];
  const float* Wk = (const float*)d_in[3];
  const float* Wv = (const float*)d_in[4];
  const float* Wq = (const float*)d_in[5];
  const float* Wo = (const float*)d_in[6];
  const float* bo = (const float*)d_in[7];
  float* out = (float*)d_out;
  char* ws = (char*)d_ws;
  const size_t MB8 = (size_t)8 * 1024 * 1024;
  u16* Qfw = (u16*)(ws);             // fragment-major Q (pre-scaled, exp2 domain)
  u16* Kfw = (u16*)(ws + MB8);       // fragment-major K
  u16* Vfw = (u16*)(ws + 2 * MB8);   // fragment-major V^T
  u16* Cw  = (u16*)(ws + 3 * MB8);   // concat [2][2048][1024]
  u16* Wot = (u16*)(ws + 4 * MB8);   // [1024][1024]

  k_transpose_wo<<<dim3(16, 16), 256, 0, stream>>>(Wo, Wot);
  k_proj<<<dim3(32, 32, 3), 256, 0, stream>>>(xq, xk, xv, Wq, Wk, Wv, Qfw, Kfw, Vfw);
  k_attn<<<512, 256, 0, stream>>>(Qfw, Kfw, Vfw, Cw);
  k_outproj<<<512, 256, 0, stream>>>(Cw, Wot, bo, out);
}

// Round 16
// 59.582 us; speedup vs baseline: 1.1696x; 1.0495x over previous
//
#include <hip/hip_runtime.h>
#include <hip/hip_bf16.h>
#include <cstdint>

typedef unsigned short u16;
typedef __bf16 bf16x8 __attribute__((ext_vector_type(8)));
typedef u16 u16x8 __attribute__((ext_vector_type(8)));
typedef unsigned u32x4 __attribute__((ext_vector_type(4)));
typedef float f32x2 __attribute__((ext_vector_type(2)));
typedef float f32x4 __attribute__((ext_vector_type(4)));
typedef float f32x16 __attribute__((ext_vector_type(16)));

#define B_ 2
#define S_ 2048
#define H_ 16
#define HS_ 64
#define EMB_ 1024
#define QSCALE 0.022097086912079608f  /* 1/sqrt(2048) */
#define LOG2E  1.4426950408889634f    /* folded into Q so softmax uses exp2 */

static __device__ __forceinline__ u16 f2bf(float f) {
  unsigned int u = __float_as_uint(f);
  u += 0x7fffu + ((u >> 16) & 1u);   // RNE
  return (u16)(u >> 16);
}

// single-instruction 2^x
static __device__ __forceinline__ float ex2(float x) {
#if __has_builtin(__builtin_amdgcn_exp2f)
  return __builtin_amdgcn_exp2f(x);
#else
  float r; asm("v_exp_f32 %0, %1" : "=v"(r) : "v"(x)); return r;
#endif
}

// depth-4 tree sum of 16 floats
static __device__ __forceinline__ float tsum16(const f32x16& s) {
  float a0 = s[0] + s[1],  a1 = s[2] + s[3];
  float a2 = s[4] + s[5],  a3 = s[6] + s[7];
  float a4 = s[8] + s[9],  a5 = s[10] + s[11];
  float a6 = s[12] + s[13], a7 = s[14] + s[15];
  a0 += a1; a2 += a3; a4 += a5; a6 += a7;
  a0 += a2; a4 += a6;
  return a0 + a4;
}

static __device__ __forceinline__ f32x4 mfma16(u16x8 a, u16x8 b, f32x4 c) {
  return __builtin_amdgcn_mfma_f32_16x16x32_bf16(
      __builtin_bit_cast(bf16x8, a), __builtin_bit_cast(bf16x8, b), c, 0, 0, 0);
}
static __device__ __forceinline__ f32x16 mfma32(u16x8 a, u16x8 b, f32x16 c) {
  return __builtin_amdgcn_mfma_f32_32x32x16_bf16(
      __builtin_bit_cast(bf16x8, a), __builtin_bit_cast(bf16x8, b), c, 0, 0, 0);
}

// XOR-swizzled address into a tile with 128B row stride (LDS bank-conflict fix).
static __device__ __forceinline__ char* swzb(void* base, int row, int colbyte) {
  return (char*)base + ((row * 128 + colbyte) ^ ((row & 7) << 4));
}
static __device__ __forceinline__ u16x8* swzp(void* base, int row, int colbyte) {
  return (u16x8*)swzb(base, row, colbyte);
}

// cvt_pk two f32 pairs to packed bf16 words, then permlane32_swap (T12).
static __device__ __forceinline__ void pk_swap(float a0, float a1, float b0, float b1,
                                               unsigned& x, unsigned& y) {
  unsigned A, Bv;
  asm("v_cvt_pk_bf16_f32 %0, %1, %2" : "=v"(A) : "v"(a0), "v"(a1));
  asm("v_cvt_pk_bf16_f32 %0, %1, %2" : "=v"(Bv) : "v"(b0), "v"(b1));
  asm("v_permlane32_swap_b32 %0, %1" : "+v"(A), "+v"(Bv));
  x = A; y = Bv;
}

// P (16 f32 = one 32-kv half-tile for one q-tile) -> two PV B-fragments
static __device__ __forceinline__ void pack2(const f32x16& s0, u16x8& pf0, u16x8& pf1) {
  unsigned w0, w1, w2, w3;
  pk_swap(s0[0], s0[1], s0[4], s0[5], w0, w2);
  pk_swap(s0[2], s0[3], s0[6], s0[7], w1, w3);
  pf0 = __builtin_bit_cast(u16x8, (u32x4){w0, w1, w2, w3});
  pk_swap(s0[8], s0[9], s0[12], s0[13], w0, w2);
  pk_swap(s0[10], s0[11], s0[14], s0[15], w1, w3);
  pf1 = __builtin_bit_cast(u16x8, (u32x4){w0, w1, w2, w3});
}

// ---------------- K1: fused Wo-transpose (z==3) + projections (z<3) ----------------
// Qf: [bh][t:64][slice:4][lane:64][8]   = Q[t*32+(l&31)][slice*16+(l>>5)*8+j] * QSCALE*LOG2E
// Kf: [bh][tau:64][slice:4][lane:64][8] = K[tau*32+(l&31)][slice*16+(l>>5)*8+j]
// Vf: [bh][j:32][eta:2][kap:4][lane:64][8] = Vt[eta*32+(l&31)][j*64+kap*16+(l>>5)*8+jj]
// Wot: [n][k] bf16 (transposed Wo), produced by the z==3 slice (16x16 blocks active).
__global__ __launch_bounds__(256) void k_proj(
    const float* __restrict__ xq, const float* __restrict__ xk, const float* __restrict__ xv,
    const float* __restrict__ Wq, const float* __restrict__ Wk, const float* __restrict__ Wv,
    const float* __restrict__ Wo,
    u16* __restrict__ Qf, u16* __restrict__ Kf, u16* __restrict__ Vf,
    u16* __restrict__ Wot) {
  __shared__ __align__(16) u16 PoolA[64 * 72];   // Xb (z<3, swz 64x64) / T (z=3, 64x72)
  __shared__ __align__(16) u16 Wb[64][64];       // Wb[e][d] = W[d][e]
  __shared__ __align__(16) u16 Tt[64][64];
  const int tn = blockIdx.z;   // 0=Q, 1=K, 2=V, 3=Wo-transpose
  const int t = threadIdx.x;
  const int r = t >> 2, c0 = (t & 3) << 4;

  if (tn == 3) {
    if (blockIdx.x >= 16 || blockIdx.y >= 16) return;
    u16 (*T)[72] = (u16(*)[72])PoolA;
    const int kb = blockIdx.y * 64, nb = blockIdx.x * 64;
    const float* src = Wo + (size_t)(kb + r) * EMB_ + nb + c0;
#pragma unroll
    for (int i = 0; i < 16; i += 4) {
      float4 f = *(const float4*)(src + i);
      T[c0 + i + 0][r] = f2bf(f.x);
      T[c0 + i + 1][r] = f2bf(f.y);
      T[c0 + i + 2][r] = f2bf(f.z);
      T[c0 + i + 3][r] = f2bf(f.w);
    }
    __syncthreads();
    u16* dst = Wot + (size_t)(nb + r) * EMB_ + kb + c0;
    *(u16x8*)(dst)     = *(const u16x8*)&T[r][c0];
    *(u16x8*)(dst + 8) = *(const u16x8*)&T[r][c0 + 8];
    return;
  }

  const int sb = blockIdx.x;   // s-block 0..31
  const int bh = blockIdx.y;   // 0..31
  const int b = bh >> 4, h = bh & 15;
  const int lane = t & 63, wv = t >> 6;
  const int lq = lane & 15, lg = lane >> 4;
  const int l31 = lane & 31, hi = lane >> 5;
  const float* xs = (tn == 0) ? xq : (tn == 1) ? xk : xv;
  const float* wsp3 = (tn == 0) ? Wq : (tn == 1) ? Wk : Wv;

  const float* src = xs + ((size_t)(b * S_ + sb * 64 + r)) * HS_ + c0;
#pragma unroll
  for (int i = 0; i < 16; i += 8) {
    float4 fa = *(const float4*)(src + i);
    float4 fb = *(const float4*)(src + i + 4);
    u16x8 v = {f2bf(fa.x), f2bf(fa.y), f2bf(fa.z), f2bf(fa.w),
               f2bf(fb.x), f2bf(fb.y), f2bf(fb.z), f2bf(fb.w)};
    *swzp(PoolA, r, (c0 + i) * 2) = v;
  }
  const float* wsp = wsp3 + ((size_t)(h * HS_ + r)) * HS_ + c0;
#pragma unroll
  for (int i = 0; i < 16; i += 4) {
    float4 f = *(const float4*)(wsp + i);
    *(u16*)swzb(Wb, c0 + i + 0, r * 2) = f2bf(f.x);
    *(u16*)swzb(Wb, c0 + i + 1, r * 2) = f2bf(f.y);
    *(u16*)swzb(Wb, c0 + i + 2, r * 2) = f2bf(f.z);
    *(u16*)swzb(Wb, c0 + i + 3, r * 2) = f2bf(f.w);
  }
  __syncthreads();
  if (tn < 2) {
    u16x8 a0 = *swzp(PoolA, wv * 16 + lq, lg * 16);
    u16x8 a1 = *swzp(PoolA, wv * 16 + lq, 64 + lg * 16);
    const float osc = (tn == 0) ? (QSCALE * LOG2E) : 1.0f;
#pragma unroll
    for (int et = 0; et < 4; ++et) {
      u16x8 b0 = *swzp(Wb, et * 16 + lq, lg * 16);
      u16x8 b1 = *swzp(Wb, et * 16 + lq, 64 + lg * 16);
      f32x4 acc = {0.f, 0.f, 0.f, 0.f};
      acc = mfma16(a0, b0, acc);
      acc = mfma16(a1, b1, acc);
#pragma unroll
      for (int rr = 0; rr < 4; ++rr)
        *(u16*)swzb(Tt, wv * 16 + lg * 4 + rr, (et * 16 + lq) * 2) = f2bf(acc[rr] * osc);
    }
  } else {
    u16x8 xb0 = *swzp(PoolA, wv * 16 + lq, lg * 16);
    u16x8 xb1 = *swzp(PoolA, wv * 16 + lq, 64 + lg * 16);
#pragma unroll
    for (int et = 0; et < 4; ++et) {
      u16x8 a0 = *swzp(Wb, et * 16 + lq, lg * 16);
      u16x8 a1 = *swzp(Wb, et * 16 + lq, 64 + lg * 16);
      f32x4 acc = {0.f, 0.f, 0.f, 0.f};
      acc = mfma16(a0, xb0, acc);
      acc = mfma16(a1, xb1, acc);
#pragma unroll
      for (int rr = 0; rr < 4; ++rr)
        *(u16*)swzb(Tt, et * 16 + lg * 4 + rr, (wv * 16 + lq) * 2) = f2bf(acc[rr]);
    }
  }
  __syncthreads();
  if (tn < 2) {
    u16* dst = (tn == 0) ? Qf : Kf;
#pragma unroll
    for (int tl = 0; tl < 2; ++tl) {
      u16x8 v = *swzp(Tt, tl * 32 + l31, wv * 32 + hi * 16);
      size_t off = (((size_t)(bh * 64 + sb * 2 + tl)) * 4 + wv) * 512 + lane * 8;
      *(u16x8*)(dst + off) = v;
    }
  } else {
#pragma unroll
    for (int eta = 0; eta < 2; ++eta) {
      u16x8 v = *swzp(Tt, eta * 32 + l31, wv * 32 + hi * 16);
      size_t off = ((((size_t)(bh * 32 + sb)) * 2 + eta) * 4 + wv) * 512 + lane * 8;
      *(u16x8*)(Vf + off) = v;
    }
  }
}

// ---------------- K2: causal flash attention, 64 q-rows/wave, 32-kv steps ----------
// R15 verbatim (best passing): R12 inner order, diag kf4/vf4 reuse, Xch[2] two-round
// merge (41KB LDS), launch_bounds(256,2) — NO forced min-wave bound (miscompiles).
__global__ __launch_bounds__(256, 2) void k_attn(
    const u16* __restrict__ Qf, const u16* __restrict__ Kf, const u16* __restrict__ Vf,
    u16* __restrict__ Co) {
  __shared__ float Xch[2][64][66];               // merge slices (two-round tree)
  __shared__ __align__(16) u16 OswE[32][64];
  __shared__ __align__(16) u16 OswO[32][64];
  const int bid = blockIdx.x;
  const int xcd = bid & 7, idx = bid >> 3;
  const int bh = (xcd << 2) | (idx & 3);
  const int p = idx >> 2;                        // 0..15
  const int b = bh >> 4, h = bh & 15;
  const int w = threadIdx.x >> 6;                // wave 0..3
  const int l = threadIdx.x & 63;
  const int lq = l & 31, hi = l >> 5;
  const float NEG = -3.0e38f;

  const u16* Kbase = Kf + ((size_t)(bh * 64) * 4) * 512 + l * 8;   // per 32-kv tau
  const u16* Vbase = Vf + ((size_t)(bh * 32) * 8) * 512 + l * 8;   // per 64-kv j

#pragma unroll 1
  for (int ph = 0; ph < 2; ++ph) {
    const int g = ph ? (31 - p) : p;
    const int n = g + 1;                         // 64-kv tiles needed
    const int js = (w * n) >> 2;
    const int je = ((w + 1) * n) >> 2;
    const bool dw = (w == 3);                    // diag owner
    const int t32s = 2 * js;
    const int t32e = dw ? 2 * (n - 1) : 2 * je;  // 32-kv loop end (diag excluded)
    const int tlim = dw ? t32e + 1 : t32e;       // prefetch validity bound

    const u16* Qe = Qf + (((size_t)(bh * 64 + 2 * g)) * 4) * 512 + l * 8;
    u16x8 qfe[4], qfo[4];
#pragma unroll
    for (int ss = 0; ss < 4; ++ss) {
      qfe[ss] = *(const u16x8*)(Qe + ss * 512);
      qfo[ss] = *(const u16x8*)(Qe + (4 + ss) * 512);
    }

    f32x16 o0e, o1e, o0o, o1o;
#pragma unroll
    for (int r = 0; r < 16; ++r) { o0e[r] = 0.f; o1e[r] = 0.f; o0o[r] = 0.f; o1o[r] = 0.f; }
    float lle = 0.f, llo = 0.f;

    u16x8 kf4[4], vf4[4];
    const bool havework = dw || (js < je);
    if (havework) {  // prologue: first 32-kv step's K and V (dw: d0 if loop empty)
      const u16* pk = Kbase + ((size_t)t32s * 4) * 512;
      size_t vb = ((size_t)(t32s >> 1) * 8 + (size_t)(t32s & 1) * 2);
#pragma unroll
      for (int ss = 0; ss < 4; ++ss) kf4[ss] = *(const u16x8*)(pk + ss * 512);
      vf4[0] = *(const u16x8*)(Vbase + (vb + 0) * 512);
      vf4[1] = *(const u16x8*)(Vbase + (vb + 1) * 512);
      vf4[2] = *(const u16x8*)(Vbase + (vb + 4) * 512);
      vf4[3] = *(const u16x8*)(Vbase + (vb + 5) * 512);
    }

    for (int t32 = t32s; t32 < t32e; ++t32) {
      const bool pre = (t32 + 1 < tlim);
      u16x8 pfA, pfB;
      f32x16 s;
      // ---- even q-tile ----
#pragma unroll
      for (int r = 0; r < 16; ++r) s[r] = -16.f;
      __builtin_amdgcn_s_setprio(1);
      s = mfma32(kf4[0], qfe[0], s);
      s = mfma32(kf4[1], qfe[1], s);
      s = mfma32(kf4[2], qfe[2], s);
      s = mfma32(kf4[3], qfe[3], s);
      __builtin_amdgcn_s_setprio(0);
#pragma unroll
      for (int r = 0; r < 16; ++r) s[r] = ex2(s[r]);
      lle += tsum16(s);
      pack2(s, pfA, pfB);
      __builtin_amdgcn_s_setprio(1);
      o0e = mfma32(vf4[0], pfA, o0e);
      o0e = mfma32(vf4[1], pfB, o0e);
      o1e = mfma32(vf4[2], pfA, o1e);
      o1e = mfma32(vf4[3], pfB, o1e);
      __builtin_amdgcn_s_setprio(0);
      // ---- odd q-tile (K dies after these issue) ----
#pragma unroll
      for (int r = 0; r < 16; ++r) s[r] = -16.f;
      __builtin_amdgcn_s_setprio(1);
      s = mfma32(kf4[0], qfo[0], s);
      s = mfma32(kf4[1], qfo[1], s);
      s = mfma32(kf4[2], qfo[2], s);
      s = mfma32(kf4[3], qfo[3], s);
      __builtin_amdgcn_s_setprio(0);
      if (pre) {  // in-place K prefetch
        const u16* pk = Kbase + ((size_t)(t32 + 1) * 4) * 512;
#pragma unroll
        for (int ss = 0; ss < 4; ++ss) kf4[ss] = *(const u16x8*)(pk + ss * 512);
      }
#pragma unroll
      for (int r = 0; r < 16; ++r) s[r] = ex2(s[r]);
      llo += tsum16(s);
      pack2(s, pfA, pfB);
      __builtin_amdgcn_s_setprio(1);
      o0o = mfma32(vf4[0], pfA, o0o);
      o0o = mfma32(vf4[1], pfB, o0o);
      o1o = mfma32(vf4[2], pfA, o1o);
      o1o = mfma32(vf4[3], pfB, o1o);
      __builtin_amdgcn_s_setprio(0);
      if (pre) {  // in-place V prefetch
        size_t vb = ((size_t)((t32 + 1) >> 1) * 8 + (size_t)((t32 + 1) & 1) * 2);
        vf4[0] = *(const u16x8*)(Vbase + (vb + 0) * 512);
        vf4[1] = *(const u16x8*)(Vbase + (vb + 1) * 512);
        vf4[2] = *(const u16x8*)(Vbase + (vb + 4) * 512);
        vf4[3] = *(const u16x8*)(Vbase + (vb + 5) * 512);
      }
    }

    if (dw) {  // peeled diag tile (kf4/vf4 hold d0): d0-even, d0-odd, then d1-odd
      u16x8 pfA, pfB;
      f32x16 s;
      // d0, even tile: triangular mask (crow > lq)
#pragma unroll
      for (int r = 0; r < 16; ++r) s[r] = -16.f;
      s = mfma32(kf4[0], qfe[0], s);
      s = mfma32(kf4[1], qfe[1], s);
      s = mfma32(kf4[2], qfe[2], s);
      s = mfma32(kf4[3], qfe[3], s);
#pragma unroll
      for (int r = 0; r < 16; ++r) {
        int crow = (r & 3) + 8 * (r >> 2) + 4 * hi;
        if (crow > lq) s[r] = NEG;
      }
#pragma unroll
      for (int r = 0; r < 16; ++r) s[r] = ex2(s[r]);
      lle += tsum16(s);
      pack2(s, pfA, pfB);
      o0e = mfma32(vf4[0], pfA, o0e);
      o0e = mfma32(vf4[1], pfB, o0e);
      o1e = mfma32(vf4[2], pfA, o1e);
      o1e = mfma32(vf4[3], pfB, o1e);
      // d0, odd tile: fully visible; after QK, kf4 dies -> reload with K[d1]
#pragma unroll
      for (int r = 0; r < 16; ++r) s[r] = -16.f;
      s = mfma32(kf4[0], qfo[0], s);
      s = mfma32(kf4[1], qfo[1], s);
      s = mfma32(kf4[2], qfo[2], s);
      s = mfma32(kf4[3], qfo[3], s);
      {
        const int t1 = 2 * n - 1;
        const u16* pk = Kbase + ((size_t)t1 * 4) * 512;
#pragma unroll
        for (int ss = 0; ss < 4; ++ss) kf4[ss] = *(const u16x8*)(pk + ss * 512);
      }
#pragma unroll
      for (int r = 0; r < 16; ++r) s[r] = ex2(s[r]);
      llo += tsum16(s);
      pack2(s, pfA, pfB);
      o0o = mfma32(vf4[0], pfA, o0o);
      o0o = mfma32(vf4[1], pfB, o0o);
      o1o = mfma32(vf4[2], pfA, o1o);
      o1o = mfma32(vf4[3], pfB, o1o);
      {  // vf4 dies after d0 PV -> reload with V[d1]
        const int t1 = 2 * n - 1;
        size_t vb = ((size_t)(t1 >> 1) * 8 + (size_t)(t1 & 1) * 2);
        vf4[0] = *(const u16x8*)(Vbase + (vb + 0) * 512);
        vf4[1] = *(const u16x8*)(Vbase + (vb + 1) * 512);
        vf4[2] = *(const u16x8*)(Vbase + (vb + 4) * 512);
        vf4[3] = *(const u16x8*)(Vbase + (vb + 5) * 512);
      }
      // d1, odd tile only (even fully masked): triangular mask
#pragma unroll
      for (int r = 0; r < 16; ++r) s[r] = -16.f;
      s = mfma32(kf4[0], qfo[0], s);
      s = mfma32(kf4[1], qfo[1], s);
      s = mfma32(kf4[2], qfo[2], s);
      s = mfma32(kf4[3], qfo[3], s);
#pragma unroll
      for (int r = 0; r < 16; ++r) {
        int crow = (r & 3) + 8 * (r >> 2) + 4 * hi;
        if (crow > lq) s[r] = NEG;
      }
#pragma unroll
      for (int r = 0; r < 16; ++r) s[r] = ex2(s[r]);
      llo += tsum16(s);
      pack2(s, pfA, pfB);
      o0o = mfma32(vf4[0], pfA, o0o);
      o0o = mfma32(vf4[1], pfB, o0o);
      o1o = mfma32(vf4[2], pfA, o1o);
      o1o = mfma32(vf4[3], pfB, o1o);
    }

    // ---- two-round tree merge (pure sums): (w0+=w1, w2+=w3) then w0+=w2 ----
    if (w == 1 || w == 3) {
      f32x2* xr = (f32x2*)(&Xch[w >> 1][l][0]);
#pragma unroll
      for (int i = 0; i < 8; ++i) {
        xr[i]      = (f32x2){o0e[2 * i], o0e[2 * i + 1]};
        xr[8 + i]  = (f32x2){o1e[2 * i], o1e[2 * i + 1]};
        xr[16 + i] = (f32x2){o0o[2 * i], o0o[2 * i + 1]};
        xr[24 + i] = (f32x2){o1o[2 * i], o1o[2 * i + 1]};
      }
      xr[32] = (f32x2){lle, llo};
    }
    __syncthreads();
    if (w == 0 || w == 2) {
      const f32x2* xr = (const f32x2*)(&Xch[w >> 1][l][0]);
#pragma unroll
      for (int i = 0; i < 8; ++i) {
        f32x2 a = xr[i], bq = xr[8 + i], c = xr[16 + i], d = xr[24 + i];
        o0e[2 * i] += a[0]; o0e[2 * i + 1] += a[1];
        o1e[2 * i] += bq[0]; o1e[2 * i + 1] += bq[1];
        o0o[2 * i] += c[0]; o0o[2 * i + 1] += c[1];
        o1o[2 * i] += d[0]; o1o[2 * i + 1] += d[1];
      }
      f32x2 e = xr[32];
      lle += e[0]; llo += e[1];
    }
    __syncthreads();
    if (w == 2) {
      f32x2* xr = (f32x2*)(&Xch[0][l][0]);
#pragma unroll
      for (int i = 0; i < 8; ++i) {
        xr[i]      = (f32x2){o0e[2 * i], o0e[2 * i + 1]};
        xr[8 + i]  = (f32x2){o1e[2 * i], o1e[2 * i + 1]};
        xr[16 + i] = (f32x2){o0o[2 * i], o0o[2 * i + 1]};
        xr[24 + i] = (f32x2){o1o[2 * i], o1o[2 * i + 1]};
      }
      xr[32] = (f32x2){lle, llo};
    }
    __syncthreads();
    if (w == 0) {
      {
        const f32x2* xr = (const f32x2*)(&Xch[0][l][0]);
#pragma unroll
        for (int i = 0; i < 8; ++i) {
          f32x2 a = xr[i], bq = xr[8 + i], c = xr[16 + i], d = xr[24 + i];
          o0e[2 * i] += a[0]; o0e[2 * i + 1] += a[1];
          o1e[2 * i] += bq[0]; o1e[2 * i + 1] += bq[1];
          o0o[2 * i] += c[0]; o0o[2 * i + 1] += c[1];
          o1o[2 * i] += d[0]; o1o[2 * i + 1] += d[1];
        }
        f32x2 e = xr[32];
        lle += e[0]; llo += e[1];
      }
      lle += __shfl_xor(lle, 32);
      llo += __shfl_xor(llo, 32);
      {
        float inv = 1.0f / lle;
#pragma unroll
        for (int r = 0; r < 16; ++r) {
          int drow = (r & 3) + 8 * (r >> 2) + 4 * hi;
          *(u16*)swzb(OswE, lq, drow * 2) = f2bf(o0e[r] * inv);
          *(u16*)swzb(OswE, lq, (32 + drow) * 2) = f2bf(o1e[r] * inv);
        }
        u16* dst = Co + ((size_t)(b * S_ + 64 * g + lq)) * EMB_ + h * HS_ + hi * 32;
#pragma unroll
        for (int k = 0; k < 4; ++k) {
          u16x8 vv = *swzp(OswE, lq, (hi * 32 + k * 8) * 2);
          *(u16x8*)(dst + k * 8) = vv;
        }
      }
      {
        float inv = 1.0f / llo;
#pragma unroll
        for (int r = 0; r < 16; ++r) {
          int drow = (r & 3) + 8 * (r >> 2) + 4 * hi;
          *(u16*)swzb(OswO, lq, drow * 2) = f2bf(o0o[r] * inv);
          *(u16*)swzb(OswO, lq, (32 + drow) * 2) = f2bf(o1o[r] * inv);
        }
        u16* dst = Co + ((size_t)(b * S_ + 64 * g + 32 + lq)) * EMB_ + h * HS_ + hi * 32;
#pragma unroll
        for (int k = 0; k < 4; ++k) {
          u16x8 vv = *swzp(OswO, lq, (hi * 32 + k * 8) * 2);
          *(u16x8*)(dst + k * 8) = vv;
        }
      }
    }
    __syncthreads();   // protect Xch/Osw before next phase
  }
}

// ---------------- K3: out = concat @ Wo + bo (fp32 out), 64x128 tiles --------------
// Staging via global_load_lds (width 16). LDS dest LINEAR; global source PRE-SWIZZLED
// (chunk' = (l&7)^(l>>3), same 128B line); fragment reads keep the XOR swizzle.
__global__ __launch_bounds__(256) void k_outproj(
    const u16* __restrict__ Cc, const u16* __restrict__ Wot,
    const float* __restrict__ bo, float* __restrict__ out) {
  __shared__ __align__(16) u16 As[64][64];
  __shared__ __align__(16) u16 Bs[128][64];
  const int bid = blockIdx.x;
  const int xcd = bid & 7, sl = bid >> 3;
  const int mb = (xcd << 3) | (sl >> 3);
  const int nb = sl & 7;
  const int t = threadIdx.x;
  const int lane = t & 63, wv = t >> 6;
  const int lq = lane & 15, lg = lane >> 4;
  const int wr = wv >> 1, wc = wv & 1;
  const int lrow = lane >> 3;                       // row within 8-row group
  const int lchk = ((lane & 7) ^ (lane >> 3)) * 8;  // pre-swizzled u16 col offset
  f32x4 acc[2][4];
#pragma unroll
  for (int mi = 0; mi < 2; ++mi)
#pragma unroll
    for (int ni = 0; ni < 4; ++ni) { f32x4 z = {0.f, 0.f, 0.f, 0.f}; acc[mi][ni] = z; }
  const u16* ga0 = Cc + (size_t)(mb * 64 + wv * 16 + lrow) * EMB_ + lchk;
  const u16* ga1 = Cc + (size_t)(mb * 64 + wv * 16 + 8 + lrow) * EMB_ + lchk;
  const u16* gb0 = Wot + (size_t)(nb * 128 + wv * 32 + lrow) * EMB_ + lchk;
  const u16* gb1 = Wot + (size_t)(nb * 128 + wv * 32 + 8 + lrow) * EMB_ + lchk;
  const u16* gb2 = Wot + (size_t)(nb * 128 + wv * 32 + 16 + lrow) * EMB_ + lchk;
  const u16* gb3 = Wot + (size_t)(nb * 128 + wv * 32 + 24 + lrow) * EMB_ + lchk;
  typedef __attribute__((address_space(3))) void lds_v;
  typedef const __attribute__((address_space(1))) void glb_v;
  for (int kt = 0; kt < 16; ++kt) {
    __syncthreads();   // previous tile's reads done
    const int co = kt * 64;
    __builtin_amdgcn_global_load_lds((glb_v*)(ga0 + co), (lds_v*)&As[wv * 16][0], 16, 0, 0);
    __builtin_amdgcn_global_load_lds((glb_v*)(ga1 + co), (lds_v*)&As[wv * 16 + 8][0], 16, 0, 0);
    __builtin_amdgcn_global_load_lds((glb_v*)(gb0 + co), (lds_v*)&Bs[wv * 32][0], 16, 0, 0);
    __builtin_amdgcn_global_load_lds((glb_v*)(gb1 + co), (lds_v*)&Bs[wv * 32 + 8][0], 16, 0, 0);
    __builtin_amdgcn_global_load_lds((glb_v*)(gb2 + co), (lds_v*)&Bs[wv * 32 + 16][0], 16, 0, 0);
    __builtin_amdgcn_global_load_lds((glb_v*)(gb3 + co), (lds_v*)&Bs[wv * 32 + 24][0], 16, 0, 0);
    __syncthreads();   // drains vmcnt (compiler emits waitcnt before barrier)
#pragma unroll
    for (int kf = 0; kf < 2; ++kf) {
      u16x8 af[2], bf[4];
#pragma unroll
      for (int mi = 0; mi < 2; ++mi)
        af[mi] = *swzp(As, wr * 32 + mi * 16 + lq, kf * 64 + lg * 16);
#pragma unroll
      for (int ni = 0; ni < 4; ++ni)
        bf[ni] = *swzp(Bs, wc * 64 + ni * 16 + lq, kf * 64 + lg * 16);
#pragma unroll
      for (int mi = 0; mi < 2; ++mi)
#pragma unroll
        for (int ni = 0; ni < 4; ++ni)
          acc[mi][ni] = mfma16(af[mi], bf[ni], acc[mi][ni]);
    }
  }
#pragma unroll
  for (int mi = 0; mi < 2; ++mi) {
#pragma unroll
    for (int ni = 0; ni < 4; ++ni) {
      int col = nb * 128 + wc * 64 + ni * 16 + lq;
      float bv = bo[col];
#pragma unroll
      for (int rr = 0; rr < 4; ++rr) {
        int row = mb * 64 + wr * 32 + mi * 16 + lg * 4 + rr;
        out[(size_t)row * EMB_ + col] = acc[mi][ni][rr] + bv;
      }
    }
  }
}

extern "C" void kernel_launch(void* const* d_in, const int* in_sizes, int n_in,
                              void* d_out, int out_size, void* d_ws, size_t ws_size,
                              hipStream_t stream) {
  const float* xk = (const float*)d_in[0];
  const float* xv = (const float*)d_in[1];
  const float* xq = (const float*)d_in[2];
  const float* Wk = (const float*)d_in[3];
  const float* Wv = (const float*)d_in[4];
  const float* Wq = (const float*)d_in[5];
  const float* Wo = (const float*)d_in[6];
  const float* bo = (const float*)d_in[7];
  float* out = (float*)d_out;
  char* ws = (char*)d_ws;
  const size_t MB8 = (size_t)8 * 1024 * 1024;
  u16* Qfw = (u16*)(ws);             // fragment-major Q (pre-scaled, exp2 domain)
  u16* Kfw = (u16*)(ws + MB8);       // fragment-major K
  u16* Vfw = (u16*)(ws + 2 * MB8);   // fragment-major V^T
  u16* Cw  = (u16*)(ws + 3 * MB8);   // concat [2][2048][1024]
  u16* Wot = (u16*)(ws + 4 * MB8);   // [1024][1024]

  k_proj<<<dim3(32, 32, 4), 256, 0, stream>>>(xq, xk, xv, Wq, Wk, Wv, Wo,
                                              Qfw, Kfw, Vfw, Wot);
  k_attn<<<512, 256, 0, stream>>>(Qfw, Kfw, Vfw, Cw);
  k_outproj<<<512, 256, 0, stream>>>(Cw, Wot, bo, out);
}